// Round 2
// baseline (10742.916 us; speedup 1.0000x reference)
//
#include <hip/hip_runtime.h>
#include <hip/hip_bf16.h>
#include <cmath>
#include <cstdint>

// ---------------------------------------------------------------------------
// CapsuleNet forward. Round 7:
//   - prim: 256x256 block, 4 waves (2x2) of 128x128 each (acc[4][4]),
//     K-step 16 -> 2x32KiB double-buffer = 64 KiB LDS -> 2 blocks/CU.
//     Counted-vmcnt pipeline: per step {stage next (8 dma16) ; s_waitcnt
//     vmcnt(8) ; s_barrier ; ds_read+MFMA ; s_barrier} -- NO vmcnt(0)
//     drain in the loop (prefetch stays in flight across barriers).
//     K-step 16 == frag k-width -> pure linear lane->slot staging (no
//     swizzle), frag reads are contiguous 1KiB ds_read_b128 (0 conflicts).
//     split-K z=14 over spatial taps (11x6 + 3x5) -> 504 blocks ~ 2/CU.
//     Single merged accumulator (W x128, act x16 => acc = 2048*C).
//   - conv1 / routing / decoder unchanged.
// ---------------------------------------------------------------------------

typedef _Float16 f16;
typedef _Float16 f16x8 __attribute__((ext_vector_type(8)));
typedef float    f32x4 __attribute__((ext_vector_type(4)));
typedef float    f32x16 __attribute__((ext_vector_type(16)));

__device__ __forceinline__ void dma16(const f16* g, f16* l)
{
    __builtin_amdgcn_global_load_lds(
        (const __attribute__((address_space(1))) void*)g,
        (__attribute__((address_space(3))) void*)l, 16, 0, 0);
}

// ------------------------- conv1 weight split: [n][k], k = c*81+khw ---------
__global__ void __launch_bounds__(256) w1split(
    const float* __restrict__ w, f16* __restrict__ wh, f16* __restrict__ wl)
{
    int idx = blockIdx.x * 256 + threadIdx.x;       // 65536
    int n = idx >> 8, k = idx & 255;
    float v = (k < 243) ? w[n * 243 + k] : 0.f;
    f16 hi = (f16)v;
    wh[idx] = hi;
    wl[idx] = (f16)((v - (float)hi) * 2048.0f);
}

// ------------------------- prim weight: permute + fp16 split ----------------
// in : w[n][c*81+khw]  -> out: whT/wlT [n][khw*256+c], values scaled x128,
// lo stored UNSCALED residual (single-accumulator scheme in prim).
__global__ void __launch_bounds__(256) transpose_split_w(
    const float* __restrict__ w, f16* __restrict__ whT, f16* __restrict__ wlT)
{
    __shared__ float tile[5184];                  // 64 c x 81 khw
    const int n  = blockIdx.x;                    // 0..255
    const int cq = blockIdx.y;                    // 0..3
    const int t  = threadIdx.x;
    const float* wr = w + (size_t)n * 20736 + cq * 5184;
    for (int i = t; i < 5184; i += 256) tile[i] = wr[i];
    __syncthreads();
    f16* oh = whT + (size_t)n * 20736 + cq * 64;
    f16* ol = wlT + (size_t)n * 20736 + cq * 64;
    for (int idx = t; idx < 648; idx += 256) {    // 81 khw x 8 c-groups
        int khw = idx >> 3, cg = idx & 7;
        f16x8 vh, vl;
#pragma unroll
        for (int e = 0; e < 8; ++e) {
            float v = tile[(cg * 8 + e) * 81 + khw] * 128.0f;
            f16 hi  = (f16)v;
            vh[e] = hi;
            vl[e] = (f16)(v - (float)hi);
        }
        *(f16x8*)&oh[khw * 256 + cg * 8] = vh;
        *(f16x8*)&ol[khw * 256 + cg * 8] = vl;
    }
}

// ------------------------- conv1: fused im2col + fp16-split MFMA ------------
// C[M=chunk*400, 256] = im2col(x)[M,256] * W1[256,256]; bias+ReLU;
// output stored as split(16*v): hh = f16(16v), hl = residual (unscaled).
__global__ void __launch_bounds__(256) conv1_mfma(
    const float* __restrict__ x,
    const f16* __restrict__ wh, const f16* __restrict__ wl,
    const float* __restrict__ bias, f16* __restrict__ hh, f16* __restrict__ hl)
{
    __shared__ __align__(16) f16 Ah[4096], Al[4096], Bh[4096], Bl[4096];
    __shared__ int otab[256];
    const int t  = threadIdx.x;
    const int m0 = blockIdx.x * 64;
    const int n0 = blockIdx.y * 64;

    {   // otab: k -> x offset (c*784 + ky*28 + kx), -1 pads
        int k = t;
        int off = -1;
        if (k < 243) {
            int c = k / 81, khw = k - c * 81;
            int ky = khw / 9, kx = khw - ky * 9;
            off = c * 784 + ky * 28 + kx;
        }
        otab[t] = off;
    }

    const int sr = t >> 3;
    const int sg = t & 7;
    const float* xb[2];
    int bbase[2], wofs[2];
#pragma unroll
    for (int pp = 0; pp < 2; ++pp) {
        int r = pp * 32 + sr;
        int m = m0 + r;
        int bb = m / 400, pix = m - bb * 400;
        int py = pix / 20, px = pix - py * 20;
        xb[pp] = x + (size_t)bb * 2352 + py * 28 + px;
        bbase[pp] = (n0 + r) * 256 + sg * 8;
        wofs[pp] = r * 64 + ((sg ^ (r & 7)) * 8);
    }

    float rx[2][8];
    f16x8 rBh[2], rBl[2];
    __syncthreads();                              // otab ready
    auto stage = [&](int s) {
#pragma unroll
        for (int pp = 0; pp < 2; ++pp) {
#pragma unroll
            for (int e = 0; e < 8; ++e) {
                int off = otab[s * 64 + sg * 8 + e];
                rx[pp][e] = (off >= 0) ? xb[pp][off] : 0.f;
            }
            rBh[pp] = *(const f16x8*)&wh[bbase[pp] + s * 64];
            rBl[pp] = *(const f16x8*)&wl[bbase[pp] + s * 64];
        }
    };

    const int lane = t & 63;
    const int wv   = t >> 6;
    const int wm   = wv >> 1, wn = wv & 1;
    const int li   = lane & 15, lq = lane >> 4;

    f32x4 acc_h[2][2], acc_x[2][2];
#pragma unroll
    for (int i = 0; i < 2; ++i)
#pragma unroll
        for (int j = 0; j < 2; ++j) {
            acc_h[i][j] = (f32x4){0.f, 0.f, 0.f, 0.f};
            acc_x[i][j] = (f32x4){0.f, 0.f, 0.f, 0.f};
        }

    stage(0);

    for (int s = 0; s < 4; ++s) {
        __syncthreads();
#pragma unroll
        for (int pp = 0; pp < 2; ++pp) {
            f16x8 vh, vl;
#pragma unroll
            for (int e = 0; e < 8; ++e) {
                float v = rx[pp][e];
                f16 hi = (f16)v;
                vh[e] = hi;
                vl[e] = (f16)((v - (float)hi) * 2048.0f);
            }
            *(f16x8*)&Ah[wofs[pp]] = vh;
            *(f16x8*)&Al[wofs[pp]] = vl;
            *(f16x8*)&Bh[wofs[pp]] = rBh[pp];
            *(f16x8*)&Bl[wofs[pp]] = rBl[pp];
        }
        __syncthreads();
        if (s + 1 < 4) stage(s + 1);
#pragma unroll
        for (int h = 0; h < 2; ++h) {
            int g = h * 4 + lq;
            f16x8 ah[2], al[2], bh[2], bl[2];
#pragma unroll
            for (int mf = 0; mf < 2; ++mf) {
                int r = wm * 32 + mf * 16 + li;
                int u = r * 64 + ((g ^ (r & 7)) * 8);
                ah[mf] = *(const f16x8*)&Ah[u];
                al[mf] = *(const f16x8*)&Al[u];
            }
#pragma unroll
            for (int nf = 0; nf < 2; ++nf) {
                int r = wn * 32 + nf * 16 + li;
                int u = r * 64 + ((g ^ (r & 7)) * 8);
                bh[nf] = *(const f16x8*)&Bh[u];
                bl[nf] = *(const f16x8*)&Bl[u];
            }
#pragma unroll
            for (int mf = 0; mf < 2; ++mf)
#pragma unroll
                for (int nf = 0; nf < 2; ++nf) {
                    acc_h[mf][nf] = __builtin_amdgcn_mfma_f32_16x16x32_f16(
                        ah[mf], bh[nf], acc_h[mf][nf], 0, 0, 0);
                    acc_x[mf][nf] = __builtin_amdgcn_mfma_f32_16x16x32_f16(
                        ah[mf], bl[nf], acc_x[mf][nf], 0, 0, 0);
                    acc_x[mf][nf] = __builtin_amdgcn_mfma_f32_16x16x32_f16(
                        al[mf], bh[nf], acc_x[mf][nf], 0, 0, 0);
                }
        }
    }

    float bn[2];
    bn[0] = bias[n0 + wn * 32 + li];
    bn[1] = bias[n0 + wn * 32 + 16 + li];
#pragma unroll
    for (int mf = 0; mf < 2; ++mf) {
        int mb = m0 + wm * 32 + mf * 16 + lq * 4;
#pragma unroll
        for (int r = 0; r < 4; ++r) {
            size_t row = (size_t)(mb + r) * 256;
#pragma unroll
            for (int nf = 0; nf < 2; ++nf) {
                int n   = n0 + wn * 32 + nf * 16 + li;
                float v = acc_h[mf][nf][r]
                        + acc_x[mf][nf][r] * (1.0f / 2048.0f) + bn[nf];
                v = fmaxf(v, 0.f) * 16.0f;        // x16 scale for prim A-side
                f16 hi = (f16)v;
                hh[row + n] = hi;
                hl[row + n] = (f16)(v - (float)hi);   // unscaled residual
            }
        }
    }
}

// ------------------------- prim conv: 4-wave 128x128, K-step 16, 2 blk/CU ---
// GEMM: C[M=chunk*36, 256] += im2col(h16)[M,Kz] * W128[Kz,256], z=14 tap
// groups. acc = (16A)(128W) = 2048*C; epilogue /2048.
// LDS/buffer (16384 f16 = 32KiB): Ah[0..4095] Al[+4096] Bh[+8192] Bl[+12288],
// each 8 chunks of (32 rows x 16 k) = 512 f16. Lane l of a dma16 lands at
// chunkbase + l*8 f16 == (row l&31, k-group l>>5) -> frag read for MFMA
// 32x32x16 is the SAME linear map: ds_read_b128 at chunkbase + l*8.
__global__ void __launch_bounds__(256, 2) prim_mfma16(
    const f16* __restrict__ hh, const f16* __restrict__ hl,
    const f16* __restrict__ whT, const f16* __restrict__ wlT,
    const float* __restrict__ bias, float* __restrict__ p, int b_base)
{
    __shared__ __align__(16) f16 lds[32768];      // 64 KiB: 2 x 16384
    const int t  = threadIdx.x;
    const int m0 = blockIdx.x * 256;
    const int zi = blockIdx.y;                    // 0..13
    const int s_begin = (zi < 11) ? zi * 6 : 66 + (zi - 11) * 5;
    const int s_cnt   = (zi < 11) ? 6 : 5;
    const int nsteps  = s_cnt * 16;               // K-steps of 16 channels

    const int l  = t & 63, w = t >> 6;            // wave 0..3
    const int wm = w >> 1, wn = w & 1;            // 2 x 2 wave grid
    const int r  = l & 31, half = l >> 5;
    const int lo8 = l * 8;                        // lane offset in chunk (f16)

    // staging source bases: wave w stages A-chunks {2w,2w+1}, B-chunks same
    int ab[2], bb2[2];
#pragma unroll
    for (int i = 0; i < 2; ++i) {
        int c  = 2 * w + i;
        int m  = m0 + 32 * c + r;
        int bm = m / 36, pix = m - bm * 36;
        int py = pix / 6, px = pix - py * 6;
        ab[i]  = (bm * 400 + py * 40 + px * 2) * 256 + half * 8;
        bb2[i] = (32 * c + r) * 20736 + half * 8;
    }

    f32x16 acc[4][4];
#pragma unroll
    for (int i = 0; i < 4; ++i)
#pragma unroll
        for (int j = 0; j < 4; ++j)
#pragma unroll
            for (int e = 0; e < 16; ++e) acc[i][j][e] = 0.f;

    auto stage = [&](int buf, int step) {
        int s  = s_begin + (step >> 4);
        int kq = step & 15;
        int ky = s / 9, kx = s - ky * 9;
        int aAdd = (ky * 20 + kx) * 256 + kq * 16;
        int bAdd = s * 256 + kq * 16;
        f16* L = &lds[buf * 16384 + w * 1024];    // wave's chunk-pair base
        dma16(hh  + ab[0]  + aAdd, L);
        dma16(hh  + ab[1]  + aAdd, L + 512);
        dma16(hl  + ab[0]  + aAdd, L + 4096);
        dma16(hl  + ab[1]  + aAdd, L + 4096 + 512);
        dma16(whT + bb2[0] + bAdd, L + 8192);
        dma16(whT + bb2[1] + bAdd, L + 8192 + 512);
        dma16(wlT + bb2[0] + bAdd, L + 12288);
        dma16(wlT + bb2[1] + bAdd, L + 12288 + 512);
    };

    stage(0, 0);                                  // 8 loads in flight

    for (int ts = 0; ts < nsteps; ++ts) {
        const int buf = ts & 1;
        if (ts + 1 < nsteps) {
            stage(buf ^ 1, ts + 1);               // +8 loads (stay in flight)
            __builtin_amdgcn_sched_barrier(0);
            asm volatile("s_waitcnt vmcnt(8)" ::: "memory");  // ts's loads done
        } else {
            asm volatile("s_waitcnt vmcnt(0)" ::: "memory");
        }
        asm volatile("s_barrier" ::: "memory");   // all waves' data landed

        const f16* LA = &lds[buf * 16384 + wm * 2048];
        const f16* LB = &lds[buf * 16384 + 8192 + wn * 2048];
        __builtin_amdgcn_s_setprio(1);
        f16x8 ah[4], al[4], bh[4], bl[4];
#pragma unroll
        for (int mf = 0; mf < 4; ++mf) {
            ah[mf] = *(const f16x8*)&LA[mf * 512 + lo8];
            al[mf] = *(const f16x8*)&LA[4096 + mf * 512 + lo8];
        }
#pragma unroll
        for (int nf = 0; nf < 4; ++nf) {
            bh[nf] = *(const f16x8*)&LB[nf * 512 + lo8];
            bl[nf] = *(const f16x8*)&LB[4096 + nf * 512 + lo8];
        }
#pragma unroll
        for (int mf = 0; mf < 4; ++mf)
#pragma unroll
            for (int nf = 0; nf < 4; ++nf) {
                acc[mf][nf] = __builtin_amdgcn_mfma_f32_32x32x16_f16(
                    ah[mf], bh[nf], acc[mf][nf], 0, 0, 0);
                acc[mf][nf] = __builtin_amdgcn_mfma_f32_32x32x16_f16(
                    ah[mf], bl[nf], acc[mf][nf], 0, 0, 0);
                acc[mf][nf] = __builtin_amdgcn_mfma_f32_32x32x16_f16(
                    al[mf], bh[nf], acc[mf][nf], 0, 0, 0);
            }
        __builtin_amdgcn_s_setprio(0);
        asm volatile("s_barrier" ::: "memory");   // reads done before overwrite
    }

    // epilogue: C/D 32x32 layout: col = lane&31, row = (reg&3)+8*(reg>>2)+4*half
    float bn[4];
#pragma unroll
    for (int nf = 0; nf < 4; ++nf) {
        int n = wn * 128 + nf * 32 + r;
        bn[nf] = (zi == 0) ? bias[n] : 0.f;
    }
#pragma unroll
    for (int mf = 0; mf < 4; ++mf) {
#pragma unroll
        for (int reg = 0; reg < 16; ++reg) {
            int row = (reg & 3) + 8 * (reg >> 2) + 4 * half;
            int mm  = m0 + wm * 128 + mf * 32 + row;
            int b2  = mm / 36, pix2 = mm - b2 * 36;
            size_t rowp = (size_t)(b_base + b2) * 9216 + pix2 * 8;
#pragma unroll
            for (int nf = 0; nf < 4; ++nf) {
                int n   = wn * 128 + nf * 32 + r;
                int cap = n >> 3, vec = n & 7;
                float v = acc[mf][nf][reg] * (1.0f / 2048.0f) + bn[nf];
                atomicAdd(&p[rowp + cap * 288 + vec], v);
            }
        }
    }
}

// ------------------------- dynamic routing (register-priors) ----------------
__global__ void __launch_bounds__(384) routing2(
    const float* __restrict__ p, const float* __restrict__ rw,
    float* __restrict__ caps)
{
    const int b = blockIdx.x;
    const int c = blockIdx.y;
    const int t = threadIdx.x;
    const int lane = t & 63, wid = t >> 6;
    __shared__ float redbuf[6];
    __shared__ float tred[6][16];
    __shared__ float outv[16];

    const float* pb  = p  + (size_t)b * 9216;
    const float* rwc = rw + (size_t)c * 147456;

    float q[3][16];
    float l[3] = {0.f, 0.f, 0.f};

#pragma unroll
    for (int j = 0; j < 3; ++j) {
        int r = t + 384 * j;
        float4 p0 = *(const float4*)&pb[r * 8];
        float4 p1 = *(const float4*)&pb[r * 8 + 4];
        float pr[8] = {p0.x, p0.y, p0.z, p0.w, p1.x, p1.y, p1.z, p1.w};
#pragma unroll
        for (int v = 0; v < 16; ++v) q[j][v] = 0.f;
        const float* wr = rwc + (size_t)r * 128;
#pragma unroll
        for (int i = 0; i < 8; ++i) {
#pragma unroll
            for (int v4 = 0; v4 < 4; ++v4) {
                float4 w4 = *(const float4*)&wr[i * 16 + v4 * 4];
                q[j][v4 * 4 + 0] = fmaf(pr[i], w4.x, q[j][v4 * 4 + 0]);
                q[j][v4 * 4 + 1] = fmaf(pr[i], w4.y, q[j][v4 * 4 + 1]);
                q[j][v4 * 4 + 2] = fmaf(pr[i], w4.z, q[j][v4 * 4 + 2]);
                q[j][v4 * 4 + 3] = fmaf(pr[i], w4.w, q[j][v4 * 4 + 3]);
            }
        }
    }

    for (int it = 0; it < 3; ++it) {
        float lm = fmaxf(fmaxf(l[0], l[1]), l[2]);
#pragma unroll
        for (int off = 32; off; off >>= 1) lm = fmaxf(lm, __shfl_down(lm, off, 64));
        __syncthreads();
        if (lane == 0) redbuf[wid] = lm;
        __syncthreads();
        lm = fmaxf(fmaxf(fmaxf(redbuf[0], redbuf[1]), fmaxf(redbuf[2], redbuf[3])),
                   fmaxf(redbuf[4], redbuf[5]));

        float e[3];
        float ls = 0.f;
#pragma unroll
        for (int j = 0; j < 3; ++j) { e[j] = __expf(l[j] - lm); ls += e[j]; }
#pragma unroll
        for (int off = 32; off; off >>= 1) ls += __shfl_down(ls, off, 64);
        __syncthreads();
        if (lane == 0) redbuf[wid] = ls;
        __syncthreads();
        ls = redbuf[0] + redbuf[1] + redbuf[2] + redbuf[3] + redbuf[4] + redbuf[5];
        const float inv = 1.f / ls;

        float tv[16];
#pragma unroll
        for (int v = 0; v < 16; ++v)
            tv[v] = fmaf(e[0], q[0][v], fmaf(e[1], q[1][v], e[2] * q[2][v]));
#pragma unroll
        for (int v = 0; v < 16; ++v) {
            float xv = tv[v];
#pragma unroll
            for (int off = 32; off; off >>= 1) xv += __shfl_down(xv, off, 64);
            tv[v] = xv;
        }
        __syncthreads();
        if (lane == 0) {
#pragma unroll
            for (int v = 0; v < 16; ++v) tred[wid][v] = tv[v];
        }
        __syncthreads();
        if (t < 16)
            outv[t] = (tred[0][t] + tred[1][t] + tred[2][t]
                     + tred[3][t] + tred[4][t] + tred[5][t]) * inv;
        __syncthreads();

        float s2 = 0.f;
#pragma unroll
        for (int v = 0; v < 16; ++v) s2 += outv[v] * outv[v];
        const float scale = s2 / ((1.f + s2) * sqrtf(s2));

        if (it == 2) {
            if (t < 16) caps[((size_t)b * 2 + c) * 16 + t] = scale * outv[t];
        } else {
            float ov[16];
#pragma unroll
            for (int v = 0; v < 16; ++v) ov[v] = scale * outv[v];
#pragma unroll
            for (int j = 0; j < 3; ++j) {
                float d = 0.f;
#pragma unroll
                for (int v = 0; v < 16; ++v) d = fmaf(q[j][v], ov[v], d);
                l[j] += d;
            }
        }
    }
}

// ------------------------- class softmax + argmax mask ----------------------
__global__ void __launch_bounds__(256) mask_kernel(
    const float* __restrict__ caps, float* __restrict__ cls_out,
    float* __restrict__ masked)
{
    int b = blockIdx.x * 256 + threadIdx.x;
    if (b < 1024) {
        const float* cb = caps + (size_t)b * 32;
        float n0 = 0.f, n1 = 0.f;
#pragma unroll
        for (int v = 0; v < 16; ++v) {
            n0 = fmaf(cb[v], cb[v], n0);
            n1 = fmaf(cb[16 + v], cb[16 + v], n1);
        }
        n0 = sqrtf(n0); n1 = sqrtf(n1);
        float mx = fmaxf(n0, n1);
        float e0 = expf(n0 - mx), e1 = expf(n1 - mx);
        float inv = 1.f / (e0 + e1);
        cls_out[b * 2 + 0] = e0 * inv;
        cls_out[b * 2 + 1] = e1 * inv;
        int cs = (n1 > n0) ? 1 : 0;
#pragma unroll
        for (int v = 0; v < 16; ++v) {
            masked[(size_t)b * 32 + v]      = (cs == 0) ? cb[v] : 0.f;
            masked[(size_t)b * 32 + 16 + v] = (cs == 1) ? cb[16 + v] : 0.f;
        }
    }
}

// ------------------------- decoder GEMM -------------------------------------
template<int ACT>
__global__ void __launch_bounds__(256) dense_gemm(
    const float* __restrict__ A, const float* __restrict__ Bw,
    const float* __restrict__ bias, float* __restrict__ out,
    int M, int N, int K)
{
    __shared__ __align__(16) float As[16][128];
    __shared__ __align__(16) float Bs[16][64];
    const int t  = threadIdx.x;
    const int m0 = blockIdx.x * 128, n0 = blockIdx.y * 64;
    const int tx = t & 15, ty = t >> 4;
    const int am = t >> 1;
    const int ak = (t & 1) * 8;
    const int nb = (t & 15) * 4, kb = t >> 4;

    float acc[8][4];
#pragma unroll
    for (int i = 0; i < 8; ++i)
#pragma unroll
        for (int j = 0; j < 4; ++j) acc[i][j] = 0.f;

    for (int k0i = 0; k0i < K; k0i += 16) {
        {
            const float* ap = A + (size_t)(m0 + am) * K + k0i + ak;
            float4 v0 = *(const float4*)ap;
            float4 v1 = *(const float4*)(ap + 4);
            As[ak + 0][am] = v0.x; As[ak + 1][am] = v0.y;
            As[ak + 2][am] = v0.z; As[ak + 3][am] = v0.w;
            As[ak + 4][am] = v1.x; As[ak + 5][am] = v1.y;
            As[ak + 6][am] = v1.z; As[ak + 7][am] = v1.w;
        }
        {
            int k = k0i + kb;
            int n = n0 + nb;
            float4 v4 = make_float4(0.f, 0.f, 0.f, 0.f);
            if (n + 3 < N) {
                v4 = *(const float4*)&Bw[(size_t)k * N + n];
            } else {
                float tmp[4] = {0.f, 0.f, 0.f, 0.f};
#pragma unroll
                for (int e = 0; e < 4; ++e)
                    if (n + e < N) tmp[e] = Bw[(size_t)k * N + n + e];
                v4 = make_float4(tmp[0], tmp[1], tmp[2], tmp[3]);
            }
            *(float4*)&Bs[kb][nb] = v4;
        }
        __syncthreads();
#pragma unroll
        for (int kk = 0; kk < 16; ++kk) {
            float4 a0 = *(const float4*)&As[kk][ty * 8];
            float4 a1 = *(const float4*)&As[kk][ty * 8 + 4];
            float4 b0 = *(const float4*)&Bs[kk][tx * 4];
            float av[8] = {a0.x, a0.y, a0.z, a0.w, a1.x, a1.y, a1.z, a1.w};
            float bv[4] = {b0.x, b0.y, b0.z, b0.w};
#pragma unroll
            for (int i = 0; i < 8; ++i)
#pragma unroll
                for (int j = 0; j < 4; ++j)
                    acc[i][j] = fmaf(av[i], bv[j], acc[i][j]);
        }
        __syncthreads();
    }
#pragma unroll
    for (int i = 0; i < 8; ++i) {
        int mm = m0 + ty * 8 + i;
#pragma unroll
        for (int j = 0; j < 4; ++j) {
            int n = n0 + tx * 4 + j;
            if (n < N) {
                float v = acc[i][j] + bias[n];
                v = (ACT == 0) ? fmaxf(v, 0.f) : 1.f / (1.f + expf(-v));
                out[(size_t)mm * N + n] = v;
            }
        }
    }
}

// ------------------------- host launcher ------------------------------------
extern "C" void kernel_launch(void* const* d_in, const int* in_sizes, int n_in,
                              void* d_out, int out_size, void* d_ws, size_t ws_size,
                              hipStream_t stream)
{
    const float* x       = (const float*)d_in[0];
    const float* conv1_w = (const float*)d_in[1];
    const float* conv1_b = (const float*)d_in[2];
    const float* prim_w  = (const float*)d_in[3];
    const float* prim_b  = (const float*)d_in[4];
    const float* route_w = (const float*)d_in[5];
    const float* dec_w1  = (const float*)d_in[6];
    const float* dec_b1  = (const float*)d_in[7];
    const float* dec_w2  = (const float*)d_in[8];
    const float* dec_b2  = (const float*)d_in[9];
    const float* dec_w3  = (const float*)d_in[10];
    const float* dec_b3  = (const float*)d_in[11];

    f16*   whT1 = (f16*)d_ws;                       //   65536 halves
    f16*   wlT1 = whT1 + 65536;
    f16*   whT  = wlT1 + 65536;                     // 5308416 halves
    f16*   wlT  = whT + 5308416;
    float* pbuf   = (float*)(wlT + 5308416);        // 9437184 f32
    float* caps   = pbuf + 9437184;
    float* masked = caps + 32768;
    float* d1     = masked + 32768;
    float* d2     = d1 + 524288;
    f16*   hbase  = (f16*)(d2 + 1048576);
    float* outF   = (float*)d_out;

    const size_t fixed_bytes = 65798144ull;
    int chunk = 64;
    const int cand[4] = {512, 256, 128, 64};
    for (int i = 0; i < 4; ++i) {
        if (fixed_bytes + (size_t)cand[i] * 409600ull <= ws_size) {
            chunk = cand[i];
            break;
        }
    }
    if (chunk > 256) chunk = 256;                   // hh/hl sized per chunk
    f16* hh = hbase;
    f16* hl = hh + (size_t)chunk * 102400;

    // p accumulated via atomics (split-K over spatial taps) -> zero it
    hipMemsetAsync(pbuf, 0, 9437184ull * sizeof(float), stream);

    w1split<<<256, 256, 0, stream>>>(conv1_w, whT1, wlT1);
    transpose_split_w<<<dim3(256, 4), 256, 0, stream>>>(prim_w, whT, wlT);

    const int nchunks = 1024 / chunk;
    for (int ci = 0; ci < nchunks; ++ci) {
        const float* xin = x + (size_t)ci * chunk * 2352;
        conv1_mfma<<<dim3(chunk * 400 / 64, 4), 256, 0, stream>>>(
            xin, whT1, wlT1, conv1_b, hh, hl);
        prim_mfma16<<<dim3(chunk * 36 / 256, 14), 256, 0, stream>>>(
            hh, hl, whT, wlT, prim_b, pbuf, ci * chunk);
    }

    routing2<<<dim3(1024, 2), 384, 0, stream>>>(pbuf, route_w, caps);
    mask_kernel<<<4, 256, 0, stream>>>(caps, outF, masked);

    dense_gemm<0><<<dim3(8, 8),  256, 0, stream>>>(masked, dec_w1, dec_b1, d1, 1024, 512, 32);
    dense_gemm<0><<<dim3(8, 16), 256, 0, stream>>>(d1, dec_w2, dec_b2, d2, 1024, 1024, 512);
    dense_gemm<1><<<dim3(8, 13), 256, 0, stream>>>(d2, dec_w3, dec_b3, outF + 2048, 1024, 784, 1024);
}

// Round 3
// 2297.009 us; speedup vs baseline: 4.6769x; 4.6769x over previous
//
#include <hip/hip_runtime.h>
#include <hip/hip_bf16.h>
#include <cmath>
#include <cstdint>

// ---------------------------------------------------------------------------
// CapsuleNet forward. Round 8 (= Round 6 structure + counted-vmcnt pipeline):
//   - prim: 256x256 block, 8 waves (2x4) of 128x64 (acc[4][2]), K-step 32,
//     double-buffered 128 KiB LDS, split-K z=7 -> 252 blocks (1/CU, clean
//     atomic coalescing, 64-B global segments). CHANGE vs R6: the per-step
//     __syncthreads() (which drains vmcnt(0), waiting the just-issued
//     prefetch) is replaced by {s_waitcnt vmcnt(8); s_barrier} at the top
//     (waits only the PREVIOUS step's 8 loads; prefetch stays in flight)
//     and a plain s_barrier after compute (protects buf from overwrite).
//   - conv1 / routing / decoder unchanged.
// Numerics: W pre-scaled x128, activations x16 => acc = 2048*C (exact pow2),
// single merged accumulator; epilogue /2048. absmax expected unchanged.
// ---------------------------------------------------------------------------

typedef _Float16 f16;
typedef _Float16 f16x8 __attribute__((ext_vector_type(8)));
typedef float    f32x4 __attribute__((ext_vector_type(4)));
typedef float    f32x16 __attribute__((ext_vector_type(16)));

__device__ __forceinline__ void dma16(const f16* g, f16* l)
{
    __builtin_amdgcn_global_load_lds(
        (const __attribute__((address_space(1))) void*)g,
        (__attribute__((address_space(3))) void*)l, 16, 0, 0);
}

// ------------------------- conv1 weight split: [n][k], k = c*81+khw ---------
__global__ void __launch_bounds__(256) w1split(
    const float* __restrict__ w, f16* __restrict__ wh, f16* __restrict__ wl)
{
    int idx = blockIdx.x * 256 + threadIdx.x;       // 65536
    int n = idx >> 8, k = idx & 255;
    float v = (k < 243) ? w[n * 243 + k] : 0.f;
    f16 hi = (f16)v;
    wh[idx] = hi;
    wl[idx] = (f16)((v - (float)hi) * 2048.0f);
}

// ------------------------- prim weight: permute + fp16 split ----------------
// in : w[n][c*81+khw]  -> out: whT/wlT [n][khw*256+c], values scaled x128,
// lo stored UNSCALED residual (single-accumulator scheme in prim).
__global__ void __launch_bounds__(256) transpose_split_w(
    const float* __restrict__ w, f16* __restrict__ whT, f16* __restrict__ wlT)
{
    __shared__ float tile[5184];                  // 64 c x 81 khw
    const int n  = blockIdx.x;                    // 0..255
    const int cq = blockIdx.y;                    // 0..3
    const int t  = threadIdx.x;
    const float* wr = w + (size_t)n * 20736 + cq * 5184;
    for (int i = t; i < 5184; i += 256) tile[i] = wr[i];
    __syncthreads();
    f16* oh = whT + (size_t)n * 20736 + cq * 64;
    f16* ol = wlT + (size_t)n * 20736 + cq * 64;
    for (int idx = t; idx < 648; idx += 256) {    // 81 khw x 8 c-groups
        int khw = idx >> 3, cg = idx & 7;
        f16x8 vh, vl;
#pragma unroll
        for (int e = 0; e < 8; ++e) {
            float v = tile[(cg * 8 + e) * 81 + khw] * 128.0f;
            f16 hi  = (f16)v;
            vh[e] = hi;
            vl[e] = (f16)(v - (float)hi);
        }
        *(f16x8*)&oh[khw * 256 + cg * 8] = vh;
        *(f16x8*)&ol[khw * 256 + cg * 8] = vl;
    }
}

// ------------------------- conv1: fused im2col + fp16-split MFMA ------------
// C[M=chunk*400, 256] = im2col(x)[M,256] * W1[256,256]; bias+ReLU;
// output stored as split(16*v): hh = f16(16v), hl = residual (unscaled).
__global__ void __launch_bounds__(256) conv1_mfma(
    const float* __restrict__ x,
    const f16* __restrict__ wh, const f16* __restrict__ wl,
    const float* __restrict__ bias, f16* __restrict__ hh, f16* __restrict__ hl)
{
    __shared__ __align__(16) f16 Ah[4096], Al[4096], Bh[4096], Bl[4096];
    __shared__ int otab[256];
    const int t  = threadIdx.x;
    const int m0 = blockIdx.x * 64;
    const int n0 = blockIdx.y * 64;

    {   // otab: k -> x offset (c*784 + ky*28 + kx), -1 pads
        int k = t;
        int off = -1;
        if (k < 243) {
            int c = k / 81, khw = k - c * 81;
            int ky = khw / 9, kx = khw - ky * 9;
            off = c * 784 + ky * 28 + kx;
        }
        otab[t] = off;
    }

    const int sr = t >> 3;
    const int sg = t & 7;
    const float* xb[2];
    int bbase[2], wofs[2];
#pragma unroll
    for (int pp = 0; pp < 2; ++pp) {
        int r = pp * 32 + sr;
        int m = m0 + r;
        int bb = m / 400, pix = m - bb * 400;
        int py = pix / 20, px = pix - py * 20;
        xb[pp] = x + (size_t)bb * 2352 + py * 28 + px;
        bbase[pp] = (n0 + r) * 256 + sg * 8;
        wofs[pp] = r * 64 + ((sg ^ (r & 7)) * 8);
    }

    float rx[2][8];
    f16x8 rBh[2], rBl[2];
    __syncthreads();                              // otab ready
    auto stage = [&](int s) {
#pragma unroll
        for (int pp = 0; pp < 2; ++pp) {
#pragma unroll
            for (int e = 0; e < 8; ++e) {
                int off = otab[s * 64 + sg * 8 + e];
                rx[pp][e] = (off >= 0) ? xb[pp][off] : 0.f;
            }
            rBh[pp] = *(const f16x8*)&wh[bbase[pp] + s * 64];
            rBl[pp] = *(const f16x8*)&wl[bbase[pp] + s * 64];
        }
    };

    const int lane = t & 63;
    const int wv   = t >> 6;
    const int wm   = wv >> 1, wn = wv & 1;
    const int li   = lane & 15, lq = lane >> 4;

    f32x4 acc_h[2][2], acc_x[2][2];
#pragma unroll
    for (int i = 0; i < 2; ++i)
#pragma unroll
        for (int j = 0; j < 2; ++j) {
            acc_h[i][j] = (f32x4){0.f, 0.f, 0.f, 0.f};
            acc_x[i][j] = (f32x4){0.f, 0.f, 0.f, 0.f};
        }

    stage(0);

    for (int s = 0; s < 4; ++s) {
        __syncthreads();
#pragma unroll
        for (int pp = 0; pp < 2; ++pp) {
            f16x8 vh, vl;
#pragma unroll
            for (int e = 0; e < 8; ++e) {
                float v = rx[pp][e];
                f16 hi = (f16)v;
                vh[e] = hi;
                vl[e] = (f16)((v - (float)hi) * 2048.0f);
            }
            *(f16x8*)&Ah[wofs[pp]] = vh;
            *(f16x8*)&Al[wofs[pp]] = vl;
            *(f16x8*)&Bh[wofs[pp]] = rBh[pp];
            *(f16x8*)&Bl[wofs[pp]] = rBl[pp];
        }
        __syncthreads();
        if (s + 1 < 4) stage(s + 1);
#pragma unroll
        for (int h = 0; h < 2; ++h) {
            int g = h * 4 + lq;
            f16x8 ah[2], al[2], bh[2], bl[2];
#pragma unroll
            for (int mf = 0; mf < 2; ++mf) {
                int r = wm * 32 + mf * 16 + li;
                int u = r * 64 + ((g ^ (r & 7)) * 8);
                ah[mf] = *(const f16x8*)&Ah[u];
                al[mf] = *(const f16x8*)&Al[u];
            }
#pragma unroll
            for (int nf = 0; nf < 2; ++nf) {
                int r = wn * 32 + nf * 16 + li;
                int u = r * 64 + ((g ^ (r & 7)) * 8);
                bh[nf] = *(const f16x8*)&Bh[u];
                bl[nf] = *(const f16x8*)&Bl[u];
            }
#pragma unroll
            for (int mf = 0; mf < 2; ++mf)
#pragma unroll
                for (int nf = 0; nf < 2; ++nf) {
                    acc_h[mf][nf] = __builtin_amdgcn_mfma_f32_16x16x32_f16(
                        ah[mf], bh[nf], acc_h[mf][nf], 0, 0, 0);
                    acc_x[mf][nf] = __builtin_amdgcn_mfma_f32_16x16x32_f16(
                        ah[mf], bl[nf], acc_x[mf][nf], 0, 0, 0);
                    acc_x[mf][nf] = __builtin_amdgcn_mfma_f32_16x16x32_f16(
                        al[mf], bh[nf], acc_x[mf][nf], 0, 0, 0);
                }
        }
    }

    float bn[2];
    bn[0] = bias[n0 + wn * 32 + li];
    bn[1] = bias[n0 + wn * 32 + 16 + li];
#pragma unroll
    for (int mf = 0; mf < 2; ++mf) {
        int mb = m0 + wm * 32 + mf * 16 + lq * 4;
#pragma unroll
        for (int r = 0; r < 4; ++r) {
            size_t row = (size_t)(mb + r) * 256;
#pragma unroll
            for (int nf = 0; nf < 2; ++nf) {
                int n   = n0 + wn * 32 + nf * 16 + li;
                float v = acc_h[mf][nf][r]
                        + acc_x[mf][nf][r] * (1.0f / 2048.0f) + bn[nf];
                v = fmaxf(v, 0.f) * 16.0f;        // x16 scale for prim A-side
                f16 hi = (f16)v;
                hh[row + n] = hi;
                hl[row + n] = (f16)(v - (float)hi);   // unscaled residual
            }
        }
    }
}

// ------------------------- prim conv: 256x256 block, single-acc, dbuf -------
// GEMM: C[M=chunk*36, 256] += im2col(h16)[M,Kz] * W128[Kz,256], summed over
// z=7 spatial-tap ranges. acc = (16A)(128W) = 2048*C; epilogue /2048.
// LDS per buffer: {Ah,Al,Bh,Bl} x 8 chunks x (32 rows x 32 k f16).
// Slot swizzle within a 2KB chunk: slot(r,c) = r + 32*((c+r)&3), c = ks*2+half
// -> frag reads (fixed c, r=lane&31) hit bank-quads r%8: conflict-free.
// global_load_lds writes linearly (slot = b2*64 + lane); the inverse perm is
// applied on the per-lane global source: c = ((2*b2+half) - (r&3)) & 3.
// Pipeline: {stage(next); vmcnt(8); s_barrier; ds_read+MFMA; s_barrier} --
// prefetch stays in flight across barriers (no vmcnt(0) drain in the loop).
__global__ void __launch_bounds__(512, 2) prim_mfma256(
    const f16* __restrict__ hh, const f16* __restrict__ hl,
    const f16* __restrict__ whT, const f16* __restrict__ wlT,
    const float* __restrict__ bias, float* __restrict__ p, int b_base)
{
    __shared__ __align__(16) f16 lds[65536];      // 128 KiB, 2 buffers
    const int t  = threadIdx.x;
    const int m0 = blockIdx.x * 256;
    const int zi = blockIdx.y;                    // 0..6
    const int s_begin = (zi < 4) ? zi * 12 : 48 + (zi - 4) * 11;
    const int s_cnt   = (zi < 4) ? 12 : 11;
    const int nsteps  = s_cnt * 8;                // K-steps of 32 channels

    const int l  = t & 63, w = t >> 6;            // wave 0..7
    const int wm = w >> 2, wn = w & 3;            // 2 x 4 wave grid
    const int r  = l & 31, half = l >> 5;

    // ---- staging lane constants: wave w stages A-chunk w and B-chunk w ----
    int m  = m0 + 32 * w + r;
    int bb = m / 36, pix = m - bb * 36;
    int py = pix / 6, px = pix - py * 6;
    const int abase = (bb * 400 + py * 40 + px * 2) * 256;   // f16 idx in hh/hl
    const int bbase = (32 * w + r) * 20736;                  // f16 idx in whT/wlT
    const int c0 = (half - (r & 3)) & 3;          // slot-col for b2 = 0
    const int c1 = (c0 + 2) & 3;                  // slot-col for b2 = 1

    // ---- frag-read lane offsets (f16 units within 1024-f16 chunk) ----
    const int j0 = (half + r) & 3;
    const int o0 = (r + 32 * j0) * 8;             // ksub 0
    const int o1 = (r + 32 * (j0 ^ 2)) * 8;       // ksub 1

    f32x16 acc[4][2];
#pragma unroll
    for (int i = 0; i < 4; ++i)
#pragma unroll
        for (int j = 0; j < 2; ++j)
#pragma unroll
            for (int e = 0; e < 16; ++e) acc[i][j][e] = 0.f;

    auto stage = [&](int buf, int step) {
        int s  = s_begin + (step >> 3);
        int kq = step & 7;
        int ky = s / 9, kx = s - ky * 9;
        int aAdd = abase + (ky * 20 + kx) * 256 + kq * 32;
        int bAdd = bbase + s * 256 + kq * 32;
        f16* L = &lds[buf * 32768 + w * 1024];
        dma16(hh  + aAdd + c0 * 8, L);                 // Ah, b2=0
        dma16(hh  + aAdd + c1 * 8, L + 512);           // Ah, b2=1
        dma16(hl  + aAdd + c0 * 8, L + 8192);          // Al
        dma16(hl  + aAdd + c1 * 8, L + 8192 + 512);
        dma16(whT + bAdd + c0 * 8, L + 16384);         // Bh
        dma16(whT + bAdd + c1 * 8, L + 16384 + 512);
        dma16(wlT + bAdd + c0 * 8, L + 24576);         // Bl
        dma16(wlT + bAdd + c1 * 8, L + 24576 + 512);
    };

    stage(0, 0);                                  // 8 loads in flight

    for (int ts = 0; ts < nsteps; ++ts) {
        const int buf = ts & 1;
        if (ts + 1 < nsteps) {
            stage(buf ^ 1, ts + 1);               // +8 loads (stay in flight)
            __builtin_amdgcn_sched_barrier(0);
            asm volatile("s_waitcnt vmcnt(8)" ::: "memory");  // ts's loads done
        } else {
            asm volatile("s_waitcnt vmcnt(0)" ::: "memory");
        }
        asm volatile("s_barrier" ::: "memory");   // all waves' data landed

        const f16* LA = &lds[buf * 32768 + wm * 4096];
        const f16* LB = &lds[buf * 32768 + 16384 + wn * 2048];
        __builtin_amdgcn_s_setprio(1);
#pragma unroll
        for (int ks = 0; ks < 2; ++ks) {
            const int o = ks ? o1 : o0;
            f16x8 ah[4], al[4], bh[2], bl[2];
#pragma unroll
            for (int mf = 0; mf < 4; ++mf) {
                ah[mf] = *(const f16x8*)&LA[mf * 1024 + o];
                al[mf] = *(const f16x8*)&LA[8192 + mf * 1024 + o];
            }
#pragma unroll
            for (int nf = 0; nf < 2; ++nf) {
                bh[nf] = *(const f16x8*)&LB[nf * 1024 + o];
                bl[nf] = *(const f16x8*)&LB[8192 + nf * 1024 + o];
            }
#pragma unroll
            for (int mf = 0; mf < 4; ++mf)
#pragma unroll
                for (int nf = 0; nf < 2; ++nf) {
                    acc[mf][nf] = __builtin_amdgcn_mfma_f32_32x32x16_f16(
                        ah[mf], bh[nf], acc[mf][nf], 0, 0, 0);
                    acc[mf][nf] = __builtin_amdgcn_mfma_f32_32x32x16_f16(
                        ah[mf], bl[nf], acc[mf][nf], 0, 0, 0);
                    acc[mf][nf] = __builtin_amdgcn_mfma_f32_32x32x16_f16(
                        al[mf], bh[nf], acc[mf][nf], 0, 0, 0);
                }
        }
        __builtin_amdgcn_s_setprio(0);
        asm volatile("s_barrier" ::: "memory");   // reads done before overwrite
    }

    // epilogue: C/D 32x32 layout: col = lane&31, row = (reg&3)+8*(reg>>2)+4*half
    float bn[2];
#pragma unroll
    for (int nf = 0; nf < 2; ++nf) {
        int n = wn * 64 + nf * 32 + r;
        bn[nf] = (zi == 0) ? bias[n] : 0.f;
    }
#pragma unroll
    for (int mf = 0; mf < 4; ++mf) {
#pragma unroll
        for (int reg = 0; reg < 16; ++reg) {
            int row = (reg & 3) + 8 * (reg >> 2) + 4 * half;
            int mm  = m0 + wm * 128 + mf * 32 + row;
            int b2  = mm / 36, pix2 = mm - b2 * 36;
            size_t rowp = (size_t)(b_base + b2) * 9216 + pix2 * 8;
#pragma unroll
            for (int nf = 0; nf < 2; ++nf) {
                int n   = wn * 64 + nf * 32 + r;
                int cap = n >> 3, vec = n & 7;
                float v = acc[mf][nf][reg] * (1.0f / 2048.0f) + bn[nf];
                atomicAdd(&p[rowp + cap * 288 + vec], v);
            }
        }
    }
}

// ------------------------- dynamic routing (register-priors) ----------------
__global__ void __launch_bounds__(384) routing2(
    const float* __restrict__ p, const float* __restrict__ rw,
    float* __restrict__ caps)
{
    const int b = blockIdx.x;
    const int c = blockIdx.y;
    const int t = threadIdx.x;
    const int lane = t & 63, wid = t >> 6;
    __shared__ float redbuf[6];
    __shared__ float tred[6][16];
    __shared__ float outv[16];

    const float* pb  = p  + (size_t)b * 9216;
    const float* rwc = rw + (size_t)c * 147456;

    float q[3][16];
    float l[3] = {0.f, 0.f, 0.f};

#pragma unroll
    for (int j = 0; j < 3; ++j) {
        int r = t + 384 * j;
        float4 p0 = *(const float4*)&pb[r * 8];
        float4 p1 = *(const float4*)&pb[r * 8 + 4];
        float pr[8] = {p0.x, p0.y, p0.z, p0.w, p1.x, p1.y, p1.z, p1.w};
#pragma unroll
        for (int v = 0; v < 16; ++v) q[j][v] = 0.f;
        const float* wr = rwc + (size_t)r * 128;
#pragma unroll
        for (int i = 0; i < 8; ++i) {
#pragma unroll
            for (int v4 = 0; v4 < 4; ++v4) {
                float4 w4 = *(const float4*)&wr[i * 16 + v4 * 4];
                q[j][v4 * 4 + 0] = fmaf(pr[i], w4.x, q[j][v4 * 4 + 0]);
                q[j][v4 * 4 + 1] = fmaf(pr[i], w4.y, q[j][v4 * 4 + 1]);
                q[j][v4 * 4 + 2] = fmaf(pr[i], w4.z, q[j][v4 * 4 + 2]);
                q[j][v4 * 4 + 3] = fmaf(pr[i], w4.w, q[j][v4 * 4 + 3]);
            }
        }
    }

    for (int it = 0; it < 3; ++it) {
        float lm = fmaxf(fmaxf(l[0], l[1]), l[2]);
#pragma unroll
        for (int off = 32; off; off >>= 1) lm = fmaxf(lm, __shfl_down(lm, off, 64));
        __syncthreads();
        if (lane == 0) redbuf[wid] = lm;
        __syncthreads();
        lm = fmaxf(fmaxf(fmaxf(redbuf[0], redbuf[1]), fmaxf(redbuf[2], redbuf[3])),
                   fmaxf(redbuf[4], redbuf[5]));

        float e[3];
        float ls = 0.f;
#pragma unroll
        for (int j = 0; j < 3; ++j) { e[j] = __expf(l[j] - lm); ls += e[j]; }
#pragma unroll
        for (int off = 32; off; off >>= 1) ls += __shfl_down(ls, off, 64);
        __syncthreads();
        if (lane == 0) redbuf[wid] = ls;
        __syncthreads();
        ls = redbuf[0] + redbuf[1] + redbuf[2] + redbuf[3] + redbuf[4] + redbuf[5];
        const float inv = 1.f / ls;

        float tv[16];
#pragma unroll
        for (int v = 0; v < 16; ++v)
            tv[v] = fmaf(e[0], q[0][v], fmaf(e[1], q[1][v], e[2] * q[2][v]));
#pragma unroll
        for (int v = 0; v < 16; ++v) {
            float xv = tv[v];
#pragma unroll
            for (int off = 32; off; off >>= 1) xv += __shfl_down(xv, off, 64);
            tv[v] = xv;
        }
        __syncthreads();
        if (lane == 0) {
#pragma unroll
            for (int v = 0; v < 16; ++v) tred[wid][v] = tv[v];
        }
        __syncthreads();
        if (t < 16)
            outv[t] = (tred[0][t] + tred[1][t] + tred[2][t]
                     + tred[3][t] + tred[4][t] + tred[5][t]) * inv;
        __syncthreads();

        float s2 = 0.f;
#pragma unroll
        for (int v = 0; v < 16; ++v) s2 += outv[v] * outv[v];
        const float scale = s2 / ((1.f + s2) * sqrtf(s2));

        if (it == 2) {
            if (t < 16) caps[((size_t)b * 2 + c) * 16 + t] = scale * outv[t];
        } else {
            float ov[16];
#pragma unroll
            for (int v = 0; v < 16; ++v) ov[v] = scale * outv[v];
#pragma unroll
            for (int j = 0; j < 3; ++j) {
                float d = 0.f;
#pragma unroll
                for (int v = 0; v < 16; ++v) d = fmaf(q[j][v], ov[v], d);
                l[j] += d;
            }
        }
    }
}

// ------------------------- class softmax + argmax mask ----------------------
__global__ void __launch_bounds__(256) mask_kernel(
    const float* __restrict__ caps, float* __restrict__ cls_out,
    float* __restrict__ masked)
{
    int b = blockIdx.x * 256 + threadIdx.x;
    if (b < 1024) {
        const float* cb = caps + (size_t)b * 32;
        float n0 = 0.f, n1 = 0.f;
#pragma unroll
        for (int v = 0; v < 16; ++v) {
            n0 = fmaf(cb[v], cb[v], n0);
            n1 = fmaf(cb[16 + v], cb[16 + v], n1);
        }
        n0 = sqrtf(n0); n1 = sqrtf(n1);
        float mx = fmaxf(n0, n1);
        float e0 = expf(n0 - mx), e1 = expf(n1 - mx);
        float inv = 1.f / (e0 + e1);
        cls_out[b * 2 + 0] = e0 * inv;
        cls_out[b * 2 + 1] = e1 * inv;
        int cs = (n1 > n0) ? 1 : 0;
#pragma unroll
        for (int v = 0; v < 16; ++v) {
            masked[(size_t)b * 32 + v]      = (cs == 0) ? cb[v] : 0.f;
            masked[(size_t)b * 32 + 16 + v] = (cs == 1) ? cb[16 + v] : 0.f;
        }
    }
}

// ------------------------- decoder GEMM -------------------------------------
template<int ACT>
__global__ void __launch_bounds__(256) dense_gemm(
    const float* __restrict__ A, const float* __restrict__ Bw,
    const float* __restrict__ bias, float* __restrict__ out,
    int M, int N, int K)
{
    __shared__ __align__(16) float As[16][128];
    __shared__ __align__(16) float Bs[16][64];
    const int t  = threadIdx.x;
    const int m0 = blockIdx.x * 128, n0 = blockIdx.y * 64;
    const int tx = t & 15, ty = t >> 4;
    const int am = t >> 1;
    const int ak = (t & 1) * 8;
    const int nb = (t & 15) * 4, kb = t >> 4;

    float acc[8][4];
#pragma unroll
    for (int i = 0; i < 8; ++i)
#pragma unroll
        for (int j = 0; j < 4; ++j) acc[i][j] = 0.f;

    for (int k0i = 0; k0i < K; k0i += 16) {
        {
            const float* ap = A + (size_t)(m0 + am) * K + k0i + ak;
            float4 v0 = *(const float4*)ap;
            float4 v1 = *(const float4*)(ap + 4);
            As[ak + 0][am] = v0.x; As[ak + 1][am] = v0.y;
            As[ak + 2][am] = v0.z; As[ak + 3][am] = v0.w;
            As[ak + 4][am] = v1.x; As[ak + 5][am] = v1.y;
            As[ak + 6][am] = v1.z; As[ak + 7][am] = v1.w;
        }
        {
            int k = k0i + kb;
            int n = n0 + nb;
            float4 v4 = make_float4(0.f, 0.f, 0.f, 0.f);
            if (n + 3 < N) {
                v4 = *(const float4*)&Bw[(size_t)k * N + n];
            } else {
                float tmp[4] = {0.f, 0.f, 0.f, 0.f};
#pragma unroll
                for (int e = 0; e < 4; ++e)
                    if (n + e < N) tmp[e] = Bw[(size_t)k * N + n + e];
                v4 = make_float4(tmp[0], tmp[1], tmp[2], tmp[3]);
            }
            *(float4*)&Bs[kb][nb] = v4;
        }
        __syncthreads();
#pragma unroll
        for (int kk = 0; kk < 16; ++kk) {
            float4 a0 = *(const float4*)&As[kk][ty * 8];
            float4 a1 = *(const float4*)&As[kk][ty * 8 + 4];
            float4 b0 = *(const float4*)&Bs[kk][tx * 4];
            float av[8] = {a0.x, a0.y, a0.z, a0.w, a1.x, a1.y, a1.z, a1.w};
            float bv[4] = {b0.x, b0.y, b0.z, b0.w};
#pragma unroll
            for (int i = 0; i < 8; ++i)
#pragma unroll
                for (int j = 0; j < 4; ++j)
                    acc[i][j] = fmaf(av[i], bv[j], acc[i][j]);
        }
        __syncthreads();
    }
#pragma unroll
    for (int i = 0; i < 8; ++i) {
        int mm = m0 + ty * 8 + i;
#pragma unroll
        for (int j = 0; j < 4; ++j) {
            int n = n0 + tx * 4 + j;
            if (n < N) {
                float v = acc[i][j] + bias[n];
                v = (ACT == 0) ? fmaxf(v, 0.f) : 1.f / (1.f + expf(-v));
                out[(size_t)mm * N + n] = v;
            }
        }
    }
}

// ------------------------- host launcher ------------------------------------
extern "C" void kernel_launch(void* const* d_in, const int* in_sizes, int n_in,
                              void* d_out, int out_size, void* d_ws, size_t ws_size,
                              hipStream_t stream)
{
    const float* x       = (const float*)d_in[0];
    const float* conv1_w = (const float*)d_in[1];
    const float* conv1_b = (const float*)d_in[2];
    const float* prim_w  = (const float*)d_in[3];
    const float* prim_b  = (const float*)d_in[4];
    const float* route_w = (const float*)d_in[5];
    const float* dec_w1  = (const float*)d_in[6];
    const float* dec_b1  = (const float*)d_in[7];
    const float* dec_w2  = (const float*)d_in[8];
    const float* dec_b2  = (const float*)d_in[9];
    const float* dec_w3  = (const float*)d_in[10];
    const float* dec_b3  = (const float*)d_in[11];

    f16*   whT1 = (f16*)d_ws;                       //   65536 halves
    f16*   wlT1 = whT1 + 65536;
    f16*   whT  = wlT1 + 65536;                     // 5308416 halves
    f16*   wlT  = whT + 5308416;
    float* pbuf   = (float*)(wlT + 5308416);        // 9437184 f32
    float* caps   = pbuf + 9437184;
    float* masked = caps + 32768;
    float* d1     = masked + 32768;
    float* d2     = d1 + 524288;
    f16*   hbase  = (f16*)(d2 + 1048576);
    float* outF   = (float*)d_out;

    const size_t fixed_bytes = 65798144ull;
    int chunk = 64;
    const int cand[4] = {512, 256, 128, 64};
    for (int i = 0; i < 4; ++i) {
        if (fixed_bytes + (size_t)cand[i] * 409600ull <= ws_size) {
            chunk = cand[i];
            break;
        }
    }
    if (chunk > 256) chunk = 256;                   // hh/hl sized per chunk
    f16* hh = hbase;
    f16* hl = hh + (size_t)chunk * 102400;

    // p accumulated via atomics (split-K over spatial taps) -> zero it
    hipMemsetAsync(pbuf, 0, 9437184ull * sizeof(float), stream);

    w1split<<<256, 256, 0, stream>>>(conv1_w, whT1, wlT1);
    transpose_split_w<<<dim3(256, 4), 256, 0, stream>>>(prim_w, whT, wlT);

    const int nchunks = 1024 / chunk;
    for (int ci = 0; ci < nchunks; ++ci) {
        const float* xin = x + (size_t)ci * chunk * 2352;
        conv1_mfma<<<dim3(chunk * 400 / 64, 4), 256, 0, stream>>>(
            xin, whT1, wlT1, conv1_b, hh, hl);
        prim_mfma256<<<dim3(chunk * 36 / 256, 7), 512, 0, stream>>>(
            hh, hl, whT, wlT, prim_b, pbuf, ci * chunk);
    }

    routing2<<<dim3(1024, 2), 384, 0, stream>>>(pbuf, route_w, caps);
    mask_kernel<<<4, 256, 0, stream>>>(caps, outF, masked);

    dense_gemm<0><<<dim3(8, 8),  256, 0, stream>>>(masked, dec_w1, dec_b1, d1, 1024, 512, 32);
    dense_gemm<0><<<dim3(8, 16), 256, 0, stream>>>(d1, dec_w2, dec_b2, d2, 1024, 1024, 512);
    dense_gemm<1><<<dim3(8, 13), 256, 0, stream>>>(d2, dec_w3, dec_b3, outF + 2048, 1024, 784, 1024);
}

// Round 4
// 2177.377 us; speedup vs baseline: 4.9339x; 1.0549x over previous
//
#include <hip/hip_runtime.h>
#include <hip/hip_bf16.h>
#include <cmath>
#include <cstdint>

// ---------------------------------------------------------------------------
// CapsuleNet forward. Round 9 (= R6 structure + MFMA dependency reorder):
//   - prim: 256x256 block, 8 waves (2x4) of 128x64 (acc[4][2]), K-step 32,
//     double-buffered 128 KiB LDS, split-K z=7, __syncthreads pipeline
//     (R6 style, measured better than counted-vmcnt in R8).
//     CHANGE: hi/lo MFMA triple reordered TERM-OUTER (all ah*bh pairs, then
//     all ah*bl, then all al*bh) -> same-acc reuse distance 1 -> 8, breaking
//     dependent-MFMA stalls. Per-acc add order unchanged => bit-identical.
//   - conv1: same reorder (distance 1 -> 4 on acc_x chains).
// Numerics: W pre-scaled x128, activations x16 => acc = 2048*C (exact pow2),
// single merged accumulator; epilogue /2048.
// ---------------------------------------------------------------------------

typedef _Float16 f16;
typedef _Float16 f16x8 __attribute__((ext_vector_type(8)));
typedef float    f32x4 __attribute__((ext_vector_type(4)));
typedef float    f32x16 __attribute__((ext_vector_type(16)));

__device__ __forceinline__ void dma16(const f16* g, f16* l)
{
    __builtin_amdgcn_global_load_lds(
        (const __attribute__((address_space(1))) void*)g,
        (__attribute__((address_space(3))) void*)l, 16, 0, 0);
}

// ------------------------- conv1 weight split: [n][k], k = c*81+khw ---------
__global__ void __launch_bounds__(256) w1split(
    const float* __restrict__ w, f16* __restrict__ wh, f16* __restrict__ wl)
{
    int idx = blockIdx.x * 256 + threadIdx.x;       // 65536
    int n = idx >> 8, k = idx & 255;
    float v = (k < 243) ? w[n * 243 + k] : 0.f;
    f16 hi = (f16)v;
    wh[idx] = hi;
    wl[idx] = (f16)((v - (float)hi) * 2048.0f);
}

// ------------------------- prim weight: permute + fp16 split ----------------
// in : w[n][c*81+khw]  -> out: whT/wlT [n][khw*256+c], values scaled x128,
// lo stored UNSCALED residual (single-accumulator scheme in prim).
__global__ void __launch_bounds__(256) transpose_split_w(
    const float* __restrict__ w, f16* __restrict__ whT, f16* __restrict__ wlT)
{
    __shared__ float tile[5184];                  // 64 c x 81 khw
    const int n  = blockIdx.x;                    // 0..255
    const int cq = blockIdx.y;                    // 0..3
    const int t  = threadIdx.x;
    const float* wr = w + (size_t)n * 20736 + cq * 5184;
    for (int i = t; i < 5184; i += 256) tile[i] = wr[i];
    __syncthreads();
    f16* oh = whT + (size_t)n * 20736 + cq * 64;
    f16* ol = wlT + (size_t)n * 20736 + cq * 64;
    for (int idx = t; idx < 648; idx += 256) {    // 81 khw x 8 c-groups
        int khw = idx >> 3, cg = idx & 7;
        f16x8 vh, vl;
#pragma unroll
        for (int e = 0; e < 8; ++e) {
            float v = tile[(cg * 8 + e) * 81 + khw] * 128.0f;
            f16 hi  = (f16)v;
            vh[e] = hi;
            vl[e] = (f16)(v - (float)hi);
        }
        *(f16x8*)&oh[khw * 256 + cg * 8] = vh;
        *(f16x8*)&ol[khw * 256 + cg * 8] = vl;
    }
}

// ------------------------- conv1: fused im2col + fp16-split MFMA ------------
// C[M=chunk*400, 256] = im2col(x)[M,256] * W1[256,256]; bias+ReLU;
// output stored as split(16*v): hh = f16(16v), hl = residual (unscaled).
__global__ void __launch_bounds__(256) conv1_mfma(
    const float* __restrict__ x,
    const f16* __restrict__ wh, const f16* __restrict__ wl,
    const float* __restrict__ bias, f16* __restrict__ hh, f16* __restrict__ hl)
{
    __shared__ __align__(16) f16 Ah[4096], Al[4096], Bh[4096], Bl[4096];
    __shared__ int otab[256];
    const int t  = threadIdx.x;
    const int m0 = blockIdx.x * 64;
    const int n0 = blockIdx.y * 64;

    {   // otab: k -> x offset (c*784 + ky*28 + kx), -1 pads
        int k = t;
        int off = -1;
        if (k < 243) {
            int c = k / 81, khw = k - c * 81;
            int ky = khw / 9, kx = khw - ky * 9;
            off = c * 784 + ky * 28 + kx;
        }
        otab[t] = off;
    }

    const int sr = t >> 3;
    const int sg = t & 7;
    const float* xb[2];
    int bbase[2], wofs[2];
#pragma unroll
    for (int pp = 0; pp < 2; ++pp) {
        int r = pp * 32 + sr;
        int m = m0 + r;
        int bb = m / 400, pix = m - bb * 400;
        int py = pix / 20, px = pix - py * 20;
        xb[pp] = x + (size_t)bb * 2352 + py * 28 + px;
        bbase[pp] = (n0 + r) * 256 + sg * 8;
        wofs[pp] = r * 64 + ((sg ^ (r & 7)) * 8);
    }

    float rx[2][8];
    f16x8 rBh[2], rBl[2];
    __syncthreads();                              // otab ready
    auto stage = [&](int s) {
#pragma unroll
        for (int pp = 0; pp < 2; ++pp) {
#pragma unroll
            for (int e = 0; e < 8; ++e) {
                int off = otab[s * 64 + sg * 8 + e];
                rx[pp][e] = (off >= 0) ? xb[pp][off] : 0.f;
            }
            rBh[pp] = *(const f16x8*)&wh[bbase[pp] + s * 64];
            rBl[pp] = *(const f16x8*)&wl[bbase[pp] + s * 64];
        }
    };

    const int lane = t & 63;
    const int wv   = t >> 6;
    const int wm   = wv >> 1, wn = wv & 1;
    const int li   = lane & 15, lq = lane >> 4;

    f32x4 acc_h[2][2], acc_x[2][2];
#pragma unroll
    for (int i = 0; i < 2; ++i)
#pragma unroll
        for (int j = 0; j < 2; ++j) {
            acc_h[i][j] = (f32x4){0.f, 0.f, 0.f, 0.f};
            acc_x[i][j] = (f32x4){0.f, 0.f, 0.f, 0.f};
        }

    stage(0);

    for (int s = 0; s < 4; ++s) {
        __syncthreads();
#pragma unroll
        for (int pp = 0; pp < 2; ++pp) {
            f16x8 vh, vl;
#pragma unroll
            for (int e = 0; e < 8; ++e) {
                float v = rx[pp][e];
                f16 hi = (f16)v;
                vh[e] = hi;
                vl[e] = (f16)((v - (float)hi) * 2048.0f);
            }
            *(f16x8*)&Ah[wofs[pp]] = vh;
            *(f16x8*)&Al[wofs[pp]] = vl;
            *(f16x8*)&Bh[wofs[pp]] = rBh[pp];
            *(f16x8*)&Bl[wofs[pp]] = rBl[pp];
        }
        __syncthreads();
        if (s + 1 < 4) stage(s + 1);
#pragma unroll
        for (int h = 0; h < 2; ++h) {
            int g = h * 4 + lq;
            f16x8 ah[2], al[2], bh[2], bl[2];
#pragma unroll
            for (int mf = 0; mf < 2; ++mf) {
                int r = wm * 32 + mf * 16 + li;
                int u = r * 64 + ((g ^ (r & 7)) * 8);
                ah[mf] = *(const f16x8*)&Ah[u];
                al[mf] = *(const f16x8*)&Al[u];
            }
#pragma unroll
            for (int nf = 0; nf < 2; ++nf) {
                int r = wn * 32 + nf * 16 + li;
                int u = r * 64 + ((g ^ (r & 7)) * 8);
                bh[nf] = *(const f16x8*)&Bh[u];
                bl[nf] = *(const f16x8*)&Bl[u];
            }
            // term-outer order: same per-acc sequence (bitwise identical),
            // same-acc reuse distance 1 -> 4 (breaks dependent-MFMA stalls)
#pragma unroll
            for (int mf = 0; mf < 2; ++mf)
#pragma unroll
                for (int nf = 0; nf < 2; ++nf)
                    acc_h[mf][nf] = __builtin_amdgcn_mfma_f32_16x16x32_f16(
                        ah[mf], bh[nf], acc_h[mf][nf], 0, 0, 0);
#pragma unroll
            for (int mf = 0; mf < 2; ++mf)
#pragma unroll
                for (int nf = 0; nf < 2; ++nf)
                    acc_x[mf][nf] = __builtin_amdgcn_mfma_f32_16x16x32_f16(
                        ah[mf], bl[nf], acc_x[mf][nf], 0, 0, 0);
#pragma unroll
            for (int mf = 0; mf < 2; ++mf)
#pragma unroll
                for (int nf = 0; nf < 2; ++nf)
                    acc_x[mf][nf] = __builtin_amdgcn_mfma_f32_16x16x32_f16(
                        al[mf], bh[nf], acc_x[mf][nf], 0, 0, 0);
        }
    }

    float bn[2];
    bn[0] = bias[n0 + wn * 32 + li];
    bn[1] = bias[n0 + wn * 32 + 16 + li];
#pragma unroll
    for (int mf = 0; mf < 2; ++mf) {
        int mb = m0 + wm * 32 + mf * 16 + lq * 4;
#pragma unroll
        for (int r = 0; r < 4; ++r) {
            size_t row = (size_t)(mb + r) * 256;
#pragma unroll
            for (int nf = 0; nf < 2; ++nf) {
                int n   = n0 + wn * 32 + nf * 16 + li;
                float v = acc_h[mf][nf][r]
                        + acc_x[mf][nf][r] * (1.0f / 2048.0f) + bn[nf];
                v = fmaxf(v, 0.f) * 16.0f;        // x16 scale for prim A-side
                f16 hi = (f16)v;
                hh[row + n] = hi;
                hl[row + n] = (f16)(v - (float)hi);   // unscaled residual
            }
        }
    }
}

// ------------------------- prim conv: 256x256 block, single-acc, dbuf -------
// GEMM: C[M=chunk*36, 256] += im2col(h16)[M,Kz] * W128[Kz,256], summed over
// z=7 spatial-tap ranges. acc = (16A)(128W) = 2048*C; epilogue /2048.
// LDS per buffer: {Ah,Al,Bh,Bl} x 8 chunks x (32 rows x 32 k f16).
// Slot swizzle within a 2KB chunk: slot(r,c) = r + 32*((c+r)&3), c = ks*2+half
// -> frag reads (fixed c, r=lane&31) hit bank-quads r%8: conflict-free.
// global_load_lds writes linearly (slot = b2*64 + lane); the inverse perm is
// applied on the per-lane global source: c = ((2*b2+half) - (r&3)) & 3.
// Pipeline: R6 style {stage(next); compute(cur); __syncthreads}.
// MFMA order: TERM-OUTER (distance-8 same-acc reuse, bit-identical result).
__global__ void __launch_bounds__(512, 2) prim_mfma256(
    const f16* __restrict__ hh, const f16* __restrict__ hl,
    const f16* __restrict__ whT, const f16* __restrict__ wlT,
    const float* __restrict__ bias, float* __restrict__ p, int b_base)
{
    __shared__ __align__(16) f16 lds[65536];      // 128 KiB, 2 buffers
    const int t  = threadIdx.x;
    const int m0 = blockIdx.x * 256;
    const int zi = blockIdx.y;                    // 0..6
    const int s_begin = (zi < 4) ? zi * 12 : 48 + (zi - 4) * 11;
    const int s_cnt   = (zi < 4) ? 12 : 11;
    const int nsteps  = s_cnt * 8;                // K-steps of 32 channels

    const int l  = t & 63, w = t >> 6;            // wave 0..7
    const int wm = w >> 2, wn = w & 3;            // 2 x 4 wave grid
    const int r  = l & 31, half = l >> 5;

    // ---- staging lane constants: wave w stages A-chunk w and B-chunk w ----
    int m  = m0 + 32 * w + r;
    int bb = m / 36, pix = m - bb * 36;
    int py = pix / 6, px = pix - py * 6;
    const int abase = (bb * 400 + py * 40 + px * 2) * 256;   // f16 idx in hh/hl
    const int bbase = (32 * w + r) * 20736;                  // f16 idx in whT/wlT
    const int c0 = (half - (r & 3)) & 3;          // slot-col for b2 = 0
    const int c1 = (c0 + 2) & 3;                  // slot-col for b2 = 1

    // ---- frag-read lane offsets (f16 units within 1024-f16 chunk) ----
    const int j0 = (half + r) & 3;
    const int o0 = (r + 32 * j0) * 8;             // ksub 0
    const int o1 = (r + 32 * (j0 ^ 2)) * 8;       // ksub 1

    f32x16 acc[4][2];
#pragma unroll
    for (int i = 0; i < 4; ++i)
#pragma unroll
        for (int j = 0; j < 2; ++j)
#pragma unroll
            for (int e = 0; e < 16; ++e) acc[i][j][e] = 0.f;

    auto stage = [&](int buf, int step) {
        int s  = s_begin + (step >> 3);
        int kq = step & 7;
        int ky = s / 9, kx = s - ky * 9;
        int aAdd = abase + (ky * 20 + kx) * 256 + kq * 32;
        int bAdd = bbase + s * 256 + kq * 32;
        f16* L = &lds[buf * 32768 + w * 1024];
        dma16(hh  + aAdd + c0 * 8, L);                 // Ah, b2=0
        dma16(hh  + aAdd + c1 * 8, L + 512);           // Ah, b2=1
        dma16(hl  + aAdd + c0 * 8, L + 8192);          // Al
        dma16(hl  + aAdd + c1 * 8, L + 8192 + 512);
        dma16(whT + bAdd + c0 * 8, L + 16384);         // Bh
        dma16(whT + bAdd + c1 * 8, L + 16384 + 512);
        dma16(wlT + bAdd + c0 * 8, L + 24576);         // Bl
        dma16(wlT + bAdd + c1 * 8, L + 24576 + 512);
    };

    stage(0, 0);
    __syncthreads();                              // buf0 visible to all waves

    for (int ts = 0; ts < nsteps; ++ts) {
        const int buf = ts & 1;
        if (ts + 1 < nsteps) stage(buf ^ 1, ts + 1);   // prefetch next step
        __builtin_amdgcn_sched_barrier(0);             // keep DMA issue early
        const f16* LA = &lds[buf * 32768 + wm * 4096];
        const f16* LB = &lds[buf * 32768 + 16384 + wn * 2048];
        __builtin_amdgcn_s_setprio(1);
#pragma unroll
        for (int ks = 0; ks < 2; ++ks) {
            const int o = ks ? o1 : o0;
            f16x8 ah[4], al[4], bh[2], bl[2];
#pragma unroll
            for (int mf = 0; mf < 4; ++mf) {
                ah[mf] = *(const f16x8*)&LA[mf * 1024 + o];
                al[mf] = *(const f16x8*)&LA[8192 + mf * 1024 + o];
            }
#pragma unroll
            for (int nf = 0; nf < 2; ++nf) {
                bh[nf] = *(const f16x8*)&LB[nf * 1024 + o];
                bl[nf] = *(const f16x8*)&LB[8192 + nf * 1024 + o];
            }
            // term-outer order: same per-acc sequence (bitwise identical),
            // same-acc reuse distance 1 -> 8 (breaks dependent-MFMA stalls)
#pragma unroll
            for (int mf = 0; mf < 4; ++mf)
#pragma unroll
                for (int nf = 0; nf < 2; ++nf)
                    acc[mf][nf] = __builtin_amdgcn_mfma_f32_32x32x16_f16(
                        ah[mf], bh[nf], acc[mf][nf], 0, 0, 0);
#pragma unroll
            for (int mf = 0; mf < 4; ++mf)
#pragma unroll
                for (int nf = 0; nf < 2; ++nf)
                    acc[mf][nf] = __builtin_amdgcn_mfma_f32_32x32x16_f16(
                        ah[mf], bl[nf], acc[mf][nf], 0, 0, 0);
#pragma unroll
            for (int mf = 0; mf < 4; ++mf)
#pragma unroll
                for (int nf = 0; nf < 2; ++nf)
                    acc[mf][nf] = __builtin_amdgcn_mfma_f32_32x32x16_f16(
                        al[mf], bh[nf], acc[mf][nf], 0, 0, 0);
        }
        __builtin_amdgcn_s_setprio(0);
        __syncthreads();                               // drains DMA + reads done
    }

    // epilogue: C/D 32x32 layout: col = lane&31, row = (reg&3)+8*(reg>>2)+4*half
    float bn[2];
#pragma unroll
    for (int nf = 0; nf < 2; ++nf) {
        int n = wn * 64 + nf * 32 + r;
        bn[nf] = (zi == 0) ? bias[n] : 0.f;
    }
#pragma unroll
    for (int mf = 0; mf < 4; ++mf) {
#pragma unroll
        for (int reg = 0; reg < 16; ++reg) {
            int row = (reg & 3) + 8 * (reg >> 2) + 4 * half;
            int mm  = m0 + wm * 128 + mf * 32 + row;
            int b2  = mm / 36, pix2 = mm - b2 * 36;
            size_t rowp = (size_t)(b_base + b2) * 9216 + pix2 * 8;
#pragma unroll
            for (int nf = 0; nf < 2; ++nf) {
                int n   = wn * 64 + nf * 32 + r;
                int cap = n >> 3, vec = n & 7;
                float v = acc[mf][nf][reg] * (1.0f / 2048.0f) + bn[nf];
                atomicAdd(&p[rowp + cap * 288 + vec], v);
            }
        }
    }
}

// ------------------------- dynamic routing (register-priors) ----------------
__global__ void __launch_bounds__(384) routing2(
    const float* __restrict__ p, const float* __restrict__ rw,
    float* __restrict__ caps)
{
    const int b = blockIdx.x;
    const int c = blockIdx.y;
    const int t = threadIdx.x;
    const int lane = t & 63, wid = t >> 6;
    __shared__ float redbuf[6];
    __shared__ float tred[6][16];
    __shared__ float outv[16];

    const float* pb  = p  + (size_t)b * 9216;
    const float* rwc = rw + (size_t)c * 147456;

    float q[3][16];
    float l[3] = {0.f, 0.f, 0.f};

#pragma unroll
    for (int j = 0; j < 3; ++j) {
        int r = t + 384 * j;
        float4 p0 = *(const float4*)&pb[r * 8];
        float4 p1 = *(const float4*)&pb[r * 8 + 4];
        float pr[8] = {p0.x, p0.y, p0.z, p0.w, p1.x, p1.y, p1.z, p1.w};
#pragma unroll
        for (int v = 0; v < 16; ++v) q[j][v] = 0.f;
        const float* wr = rwc + (size_t)r * 128;
#pragma unroll
        for (int i = 0; i < 8; ++i) {
#pragma unroll
            for (int v4 = 0; v4 < 4; ++v4) {
                float4 w4 = *(const float4*)&wr[i * 16 + v4 * 4];
                q[j][v4 * 4 + 0] = fmaf(pr[i], w4.x, q[j][v4 * 4 + 0]);
                q[j][v4 * 4 + 1] = fmaf(pr[i], w4.y, q[j][v4 * 4 + 1]);
                q[j][v4 * 4 + 2] = fmaf(pr[i], w4.z, q[j][v4 * 4 + 2]);
                q[j][v4 * 4 + 3] = fmaf(pr[i], w4.w, q[j][v4 * 4 + 3]);
            }
        }
    }

    for (int it = 0; it < 3; ++it) {
        float lm = fmaxf(fmaxf(l[0], l[1]), l[2]);
#pragma unroll
        for (int off = 32; off; off >>= 1) lm = fmaxf(lm, __shfl_down(lm, off, 64));
        __syncthreads();
        if (lane == 0) redbuf[wid] = lm;
        __syncthreads();
        lm = fmaxf(fmaxf(fmaxf(redbuf[0], redbuf[1]), fmaxf(redbuf[2], redbuf[3])),
                   fmaxf(redbuf[4], redbuf[5]));

        float e[3];
        float ls = 0.f;
#pragma unroll
        for (int j = 0; j < 3; ++j) { e[j] = __expf(l[j] - lm); ls += e[j]; }
#pragma unroll
        for (int off = 32; off; off >>= 1) ls += __shfl_down(ls, off, 64);
        __syncthreads();
        if (lane == 0) redbuf[wid] = ls;
        __syncthreads();
        ls = redbuf[0] + redbuf[1] + redbuf[2] + redbuf[3] + redbuf[4] + redbuf[5];
        const float inv = 1.f / ls;

        float tv[16];
#pragma unroll
        for (int v = 0; v < 16; ++v)
            tv[v] = fmaf(e[0], q[0][v], fmaf(e[1], q[1][v], e[2] * q[2][v]));
#pragma unroll
        for (int v = 0; v < 16; ++v) {
            float xv = tv[v];
#pragma unroll
            for (int off = 32; off; off >>= 1) xv += __shfl_down(xv, off, 64);
            tv[v] = xv;
        }
        __syncthreads();
        if (lane == 0) {
#pragma unroll
            for (int v = 0; v < 16; ++v) tred[wid][v] = tv[v];
        }
        __syncthreads();
        if (t < 16)
            outv[t] = (tred[0][t] + tred[1][t] + tred[2][t]
                     + tred[3][t] + tred[4][t] + tred[5][t]) * inv;
        __syncthreads();

        float s2 = 0.f;
#pragma unroll
        for (int v = 0; v < 16; ++v) s2 += outv[v] * outv[v];
        const float scale = s2 / ((1.f + s2) * sqrtf(s2));

        if (it == 2) {
            if (t < 16) caps[((size_t)b * 2 + c) * 16 + t] = scale * outv[t];
        } else {
            float ov[16];
#pragma unroll
            for (int v = 0; v < 16; ++v) ov[v] = scale * outv[v];
#pragma unroll
            for (int j = 0; j < 3; ++j) {
                float d = 0.f;
#pragma unroll
                for (int v = 0; v < 16; ++v) d = fmaf(q[j][v], ov[v], d);
                l[j] += d;
            }
        }
    }
}

// ------------------------- class softmax + argmax mask ----------------------
__global__ void __launch_bounds__(256) mask_kernel(
    const float* __restrict__ caps, float* __restrict__ cls_out,
    float* __restrict__ masked)
{
    int b = blockIdx.x * 256 + threadIdx.x;
    if (b < 1024) {
        const float* cb = caps + (size_t)b * 32;
        float n0 = 0.f, n1 = 0.f;
#pragma unroll
        for (int v = 0; v < 16; ++v) {
            n0 = fmaf(cb[v], cb[v], n0);
            n1 = fmaf(cb[16 + v], cb[16 + v], n1);
        }
        n0 = sqrtf(n0); n1 = sqrtf(n1);
        float mx = fmaxf(n0, n1);
        float e0 = expf(n0 - mx), e1 = expf(n1 - mx);
        float inv = 1.f / (e0 + e1);
        cls_out[b * 2 + 0] = e0 * inv;
        cls_out[b * 2 + 1] = e1 * inv;
        int cs = (n1 > n0) ? 1 : 0;
#pragma unroll
        for (int v = 0; v < 16; ++v) {
            masked[(size_t)b * 32 + v]      = (cs == 0) ? cb[v] : 0.f;
            masked[(size_t)b * 32 + 16 + v] = (cs == 1) ? cb[16 + v] : 0.f;
        }
    }
}

// ------------------------- decoder GEMM -------------------------------------
template<int ACT>
__global__ void __launch_bounds__(256) dense_gemm(
    const float* __restrict__ A, const float* __restrict__ Bw,
    const float* __restrict__ bias, float* __restrict__ out,
    int M, int N, int K)
{
    __shared__ __align__(16) float As[16][128];
    __shared__ __align__(16) float Bs[16][64];
    const int t  = threadIdx.x;
    const int m0 = blockIdx.x * 128, n0 = blockIdx.y * 64;
    const int tx = t & 15, ty = t >> 4;
    const int am = t >> 1;
    const int ak = (t & 1) * 8;
    const int nb = (t & 15) * 4, kb = t >> 4;

    float acc[8][4];
#pragma unroll
    for (int i = 0; i < 8; ++i)
#pragma unroll
        for (int j = 0; j < 4; ++j) acc[i][j] = 0.f;

    for (int k0i = 0; k0i < K; k0i += 16) {
        {
            const float* ap = A + (size_t)(m0 + am) * K + k0i + ak;
            float4 v0 = *(const float4*)ap;
            float4 v1 = *(const float4*)(ap + 4);
            As[ak + 0][am] = v0.x; As[ak + 1][am] = v0.y;
            As[ak + 2][am] = v0.z; As[ak + 3][am] = v0.w;
            As[ak + 4][am] = v1.x; As[ak + 5][am] = v1.y;
            As[ak + 6][am] = v1.z; As[ak + 7][am] = v1.w;
        }
        {
            int k = k0i + kb;
            int n = n0 + nb;
            float4 v4 = make_float4(0.f, 0.f, 0.f, 0.f);
            if (n + 3 < N) {
                v4 = *(const float4*)&Bw[(size_t)k * N + n];
            } else {
                float tmp[4] = {0.f, 0.f, 0.f, 0.f};
#pragma unroll
                for (int e = 0; e < 4; ++e)
                    if (n + e < N) tmp[e] = Bw[(size_t)k * N + n + e];
                v4 = make_float4(tmp[0], tmp[1], tmp[2], tmp[3]);
            }
            *(float4*)&Bs[kb][nb] = v4;
        }
        __syncthreads();
#pragma unroll
        for (int kk = 0; kk < 16; ++kk) {
            float4 a0 = *(const float4*)&As[kk][ty * 8];
            float4 a1 = *(const float4*)&As[kk][ty * 8 + 4];
            float4 b0 = *(const float4*)&Bs[kk][tx * 4];
            float av[8] = {a0.x, a0.y, a0.z, a0.w, a1.x, a1.y, a1.z, a1.w};
            float bv[4] = {b0.x, b0.y, b0.z, b0.w};
#pragma unroll
            for (int i = 0; i < 8; ++i)
#pragma unroll
                for (int j = 0; j < 4; ++j)
                    acc[i][j] = fmaf(av[i], bv[j], acc[i][j]);
        }
        __syncthreads();
    }
#pragma unroll
    for (int i = 0; i < 8; ++i) {
        int mm = m0 + ty * 8 + i;
#pragma unroll
        for (int j = 0; j < 4; ++j) {
            int n = n0 + tx * 4 + j;
            if (n < N) {
                float v = acc[i][j] + bias[n];
                v = (ACT == 0) ? fmaxf(v, 0.f) : 1.f / (1.f + expf(-v));
                out[(size_t)mm * N + n] = v;
            }
        }
    }
}

// ------------------------- host launcher ------------------------------------
extern "C" void kernel_launch(void* const* d_in, const int* in_sizes, int n_in,
                              void* d_out, int out_size, void* d_ws, size_t ws_size,
                              hipStream_t stream)
{
    const float* x       = (const float*)d_in[0];
    const float* conv1_w = (const float*)d_in[1];
    const float* conv1_b = (const float*)d_in[2];
    const float* prim_w  = (const float*)d_in[3];
    const float* prim_b  = (const float*)d_in[4];
    const float* route_w = (const float*)d_in[5];
    const float* dec_w1  = (const float*)d_in[6];
    const float* dec_b1  = (const float*)d_in[7];
    const float* dec_w2  = (const float*)d_in[8];
    const float* dec_b2  = (const float*)d_in[9];
    const float* dec_w3  = (const float*)d_in[10];
    const float* dec_b3  = (const float*)d_in[11];

    f16*   whT1 = (f16*)d_ws;                       //   65536 halves
    f16*   wlT1 = whT1 + 65536;
    f16*   whT  = wlT1 + 65536;                     // 5308416 halves
    f16*   wlT  = whT + 5308416;
    float* pbuf   = (float*)(wlT + 5308416);        // 9437184 f32
    float* caps   = pbuf + 9437184;
    float* masked = caps + 32768;
    float* d1     = masked + 32768;
    float* d2     = d1 + 524288;
    f16*   hbase  = (f16*)(d2 + 1048576);
    float* outF   = (float*)d_out;

    const size_t fixed_bytes = 65798144ull;
    int chunk = 64;
    const int cand[4] = {512, 256, 128, 64};
    for (int i = 0; i < 4; ++i) {
        if (fixed_bytes + (size_t)cand[i] * 409600ull <= ws_size) {
            chunk = cand[i];
            break;
        }
    }
    if (chunk > 256) chunk = 256;                   // hh/hl sized per chunk
    f16* hh = hbase;
    f16* hl = hh + (size_t)chunk * 102400;

    // p accumulated via atomics (split-K) -> zero it
    hipMemsetAsync(pbuf, 0, 9437184ull * sizeof(float), stream);

    w1split<<<256, 256, 0, stream>>>(conv1_w, whT1, wlT1);
    transpose_split_w<<<dim3(256, 4), 256, 0, stream>>>(prim_w, whT, wlT);

    const int nchunks = 1024 / chunk;
    for (int ci = 0; ci < nchunks; ++ci) {
        const float* xin = x + (size_t)ci * chunk * 2352;
        conv1_mfma<<<dim3(chunk * 400 / 64, 4), 256, 0, stream>>>(
            xin, whT1, wlT1, conv1_b, hh, hl);
        prim_mfma256<<<dim3(chunk * 36 / 256, 7), 512, 0, stream>>>(
            hh, hl, whT, wlT, prim_b, pbuf, ci * chunk);
    }

    routing2<<<dim3(1024, 2), 384, 0, stream>>>(pbuf, route_w, caps);
    mask_kernel<<<4, 256, 0, stream>>>(caps, outF, masked);

    dense_gemm<0><<<dim3(8, 8),  256, 0, stream>>>(masked, dec_w1, dec_b1, d1, 1024, 512, 32);
    dense_gemm<0><<<dim3(8, 16), 256, 0, stream>>>(d1, dec_w2, dec_b2, d2, 1024, 1024, 512);
    dense_gemm<1><<<dim3(8, 13), 256, 0, stream>>>(d2, dec_w3, dec_b3, outF + 2048, 1024, 784, 1024);
}

// Round 5
// 1924.557 us; speedup vs baseline: 5.5820x; 1.1314x over previous
//
#include <hip/hip_runtime.h>
#include <hip/hip_bf16.h>
#include <cmath>
#include <cstdint>

// ---------------------------------------------------------------------------
// CapsuleNet forward. Round 10 (= R9 structure, A-residual path DELETED):
//   - Numerics: C = A*W computed as ah*bh + ah*bl where ah = f16(16*A),
//     {bh,bl} = f16 split of 128*W. ah*(bh+bl) reconstructs W to ~2^-22;
//     the dropped A-residual term contributes ~1e-4 abs on priors
//     (40x under measured absmax). acc = 2048*C, epilogue /2048.
//   - prim: 256x256 block, 8 waves (2x4) of 128x64 (acc[4][2]), K-step 32,
//     double-buffered 96 KiB LDS {Ah,Bh,Bl}, 6 dma16/step/wave, split-K
//     z=7, __syncthreads pipeline (measured best), term-outer MFMA order.
//     2 MFMA products per acc (was 3).
//   - conv1: no Al staging, no hl store; 2-term MFMA (acc_h=ah*bh,
//     acc_x=ah*bl).
// ---------------------------------------------------------------------------

typedef _Float16 f16;
typedef _Float16 f16x8 __attribute__((ext_vector_type(8)));
typedef float    f32x4 __attribute__((ext_vector_type(4)));
typedef float    f32x16 __attribute__((ext_vector_type(16)));

__device__ __forceinline__ void dma16(const f16* g, f16* l)
{
    __builtin_amdgcn_global_load_lds(
        (const __attribute__((address_space(1))) void*)g,
        (__attribute__((address_space(3))) void*)l, 16, 0, 0);
}

// ------------------------- conv1 weight split: [n][k], k = c*81+khw ---------
__global__ void __launch_bounds__(256) w1split(
    const float* __restrict__ w, f16* __restrict__ wh, f16* __restrict__ wl)
{
    int idx = blockIdx.x * 256 + threadIdx.x;       // 65536
    int n = idx >> 8, k = idx & 255;
    float v = (k < 243) ? w[n * 243 + k] : 0.f;
    f16 hi = (f16)v;
    wh[idx] = hi;
    wl[idx] = (f16)((v - (float)hi) * 2048.0f);
}

// ------------------------- prim weight: permute + fp16 split ----------------
// in : w[n][c*81+khw]  -> out: whT/wlT [n][khw*256+c], values scaled x128,
// lo stored UNSCALED residual.
__global__ void __launch_bounds__(256) transpose_split_w(
    const float* __restrict__ w, f16* __restrict__ whT, f16* __restrict__ wlT)
{
    __shared__ float tile[5184];                  // 64 c x 81 khw
    const int n  = blockIdx.x;                    // 0..255
    const int cq = blockIdx.y;                    // 0..3
    const int t  = threadIdx.x;
    const float* wr = w + (size_t)n * 20736 + cq * 5184;
    for (int i = t; i < 5184; i += 256) tile[i] = wr[i];
    __syncthreads();
    f16* oh = whT + (size_t)n * 20736 + cq * 64;
    f16* ol = wlT + (size_t)n * 20736 + cq * 64;
    for (int idx = t; idx < 648; idx += 256) {    // 81 khw x 8 c-groups
        int khw = idx >> 3, cg = idx & 7;
        f16x8 vh, vl;
#pragma unroll
        for (int e = 0; e < 8; ++e) {
            float v = tile[(cg * 8 + e) * 81 + khw] * 128.0f;
            f16 hi  = (f16)v;
            vh[e] = hi;
            vl[e] = (f16)(v - (float)hi);
        }
        *(f16x8*)&oh[khw * 256 + cg * 8] = vh;
        *(f16x8*)&ol[khw * 256 + cg * 8] = vl;
    }
}

// ------------------------- conv1: fused im2col + fp16-split MFMA ------------
// C[M=chunk*400, 256] = im2col(x)[M,256] * W1[256,256]; bias+ReLU;
// output stored as hh = f16(16*v) only (no residual stream).
__global__ void __launch_bounds__(256) conv1_mfma(
    const float* __restrict__ x,
    const f16* __restrict__ wh, const f16* __restrict__ wl,
    const float* __restrict__ bias, f16* __restrict__ hh)
{
    __shared__ __align__(16) f16 Ah[4096], Bh[4096], Bl[4096];
    __shared__ int otab[256];
    const int t  = threadIdx.x;
    const int m0 = blockIdx.x * 64;
    const int n0 = blockIdx.y * 64;

    {   // otab: k -> x offset (c*784 + ky*28 + kx), -1 pads
        int k = t;
        int off = -1;
        if (k < 243) {
            int c = k / 81, khw = k - c * 81;
            int ky = khw / 9, kx = khw - ky * 9;
            off = c * 784 + ky * 28 + kx;
        }
        otab[t] = off;
    }

    const int sr = t >> 3;
    const int sg = t & 7;
    const float* xb[2];
    int bbase[2], wofs[2];
#pragma unroll
    for (int pp = 0; pp < 2; ++pp) {
        int r = pp * 32 + sr;
        int m = m0 + r;
        int bb = m / 400, pix = m - bb * 400;
        int py = pix / 20, px = pix - py * 20;
        xb[pp] = x + (size_t)bb * 2352 + py * 28 + px;
        bbase[pp] = (n0 + r) * 256 + sg * 8;
        wofs[pp] = r * 64 + ((sg ^ (r & 7)) * 8);
    }

    float rx[2][8];
    f16x8 rBh[2], rBl[2];
    __syncthreads();                              // otab ready
    auto stage = [&](int s) {
#pragma unroll
        for (int pp = 0; pp < 2; ++pp) {
#pragma unroll
            for (int e = 0; e < 8; ++e) {
                int off = otab[s * 64 + sg * 8 + e];
                rx[pp][e] = (off >= 0) ? xb[pp][off] : 0.f;
            }
            rBh[pp] = *(const f16x8*)&wh[bbase[pp] + s * 64];
            rBl[pp] = *(const f16x8*)&wl[bbase[pp] + s * 64];
        }
    };

    const int lane = t & 63;
    const int wv   = t >> 6;
    const int wm   = wv >> 1, wn = wv & 1;
    const int li   = lane & 15, lq = lane >> 4;

    f32x4 acc_h[2][2], acc_x[2][2];
#pragma unroll
    for (int i = 0; i < 2; ++i)
#pragma unroll
        for (int j = 0; j < 2; ++j) {
            acc_h[i][j] = (f32x4){0.f, 0.f, 0.f, 0.f};
            acc_x[i][j] = (f32x4){0.f, 0.f, 0.f, 0.f};
        }

    stage(0);

    for (int s = 0; s < 4; ++s) {
        __syncthreads();
#pragma unroll
        for (int pp = 0; pp < 2; ++pp) {
            f16x8 vh;
#pragma unroll
            for (int e = 0; e < 8; ++e) vh[e] = (f16)rx[pp][e];
            *(f16x8*)&Ah[wofs[pp]] = vh;
            *(f16x8*)&Bh[wofs[pp]] = rBh[pp];
            *(f16x8*)&Bl[wofs[pp]] = rBl[pp];
        }
        __syncthreads();
        if (s + 1 < 4) stage(s + 1);
#pragma unroll
        for (int h = 0; h < 2; ++h) {
            int g = h * 4 + lq;
            f16x8 ah[2], bh[2], bl[2];
#pragma unroll
            for (int mf = 0; mf < 2; ++mf) {
                int r = wm * 32 + mf * 16 + li;
                int u = r * 64 + ((g ^ (r & 7)) * 8);
                ah[mf] = *(const f16x8*)&Ah[u];
            }
#pragma unroll
            for (int nf = 0; nf < 2; ++nf) {
                int r = wn * 32 + nf * 16 + li;
                int u = r * 64 + ((g ^ (r & 7)) * 8);
                bh[nf] = *(const f16x8*)&Bh[u];
                bl[nf] = *(const f16x8*)&Bl[u];
            }
            // term-outer order (distance-4 same-acc reuse)
#pragma unroll
            for (int mf = 0; mf < 2; ++mf)
#pragma unroll
                for (int nf = 0; nf < 2; ++nf)
                    acc_h[mf][nf] = __builtin_amdgcn_mfma_f32_16x16x32_f16(
                        ah[mf], bh[nf], acc_h[mf][nf], 0, 0, 0);
#pragma unroll
            for (int mf = 0; mf < 2; ++mf)
#pragma unroll
                for (int nf = 0; nf < 2; ++nf)
                    acc_x[mf][nf] = __builtin_amdgcn_mfma_f32_16x16x32_f16(
                        ah[mf], bl[nf], acc_x[mf][nf], 0, 0, 0);
        }
    }

    float bn[2];
    bn[0] = bias[n0 + wn * 32 + li];
    bn[1] = bias[n0 + wn * 32 + 16 + li];
#pragma unroll
    for (int mf = 0; mf < 2; ++mf) {
        int mb = m0 + wm * 32 + mf * 16 + lq * 4;
#pragma unroll
        for (int r = 0; r < 4; ++r) {
            size_t row = (size_t)(mb + r) * 256;
#pragma unroll
            for (int nf = 0; nf < 2; ++nf) {
                int n   = n0 + wn * 32 + nf * 16 + li;
                float v = acc_h[mf][nf][r]
                        + acc_x[mf][nf][r] * (1.0f / 2048.0f) + bn[nf];
                v = fmaxf(v, 0.f) * 16.0f;        // x16 scale for prim A-side
                hh[row + n] = (f16)v;
            }
        }
    }
}

// ------------------------- prim conv: 256x256 block, 2-term, dbuf -----------
// GEMM: C[M=chunk*36, 256] += im2col(h16)[M,Kz] * W128[Kz,256], summed over
// z=7 spatial-tap ranges. acc = (16A)(128W) = 2048*C; epilogue /2048.
// LDS per buffer (24576 f16 = 48 KiB): Ah[0..8191] Bh[+8192] Bl[+16384],
// each 8 chunks x (32 rows x 32 k f16).
// Slot swizzle within a 2KB chunk: slot(r,c) = r + 32*((c+r)&3), c = ks*2+half
// -> frag reads (fixed c, r=lane&31) conflict-free. global_load_lds writes
// linearly; inverse perm applied on per-lane global source column c0/c1.
// Pipeline: {stage(next); compute(cur); __syncthreads} (measured best).
__global__ void __launch_bounds__(512, 2) prim_mfma256(
    const f16* __restrict__ hh,
    const f16* __restrict__ whT, const f16* __restrict__ wlT,
    const float* __restrict__ bias, float* __restrict__ p, int b_base)
{
    __shared__ __align__(16) f16 lds[49152];      // 96 KiB, 2 buffers a 24576
    const int t  = threadIdx.x;
    const int m0 = blockIdx.x * 256;
    const int zi = blockIdx.y;                    // 0..6
    const int s_begin = (zi < 4) ? zi * 12 : 48 + (zi - 4) * 11;
    const int s_cnt   = (zi < 4) ? 12 : 11;
    const int nsteps  = s_cnt * 8;                // K-steps of 32 channels

    const int l  = t & 63, w = t >> 6;            // wave 0..7
    const int wm = w >> 2, wn = w & 3;            // 2 x 4 wave grid
    const int r  = l & 31, half = l >> 5;

    // ---- staging lane constants: wave w stages A-chunk w and B-chunk w ----
    int m  = m0 + 32 * w + r;
    int bb = m / 36, pix = m - bb * 36;
    int py = pix / 6, px = pix - py * 6;
    const int abase = (bb * 400 + py * 40 + px * 2) * 256;   // f16 idx in hh
    const int bbase = (32 * w + r) * 20736;                  // f16 idx in whT/wlT
    const int c0 = (half - (r & 3)) & 3;          // slot-col for b2 = 0
    const int c1 = (c0 + 2) & 3;                  // slot-col for b2 = 1

    // ---- frag-read lane offsets (f16 units within 1024-f16 chunk) ----
    const int j0 = (half + r) & 3;
    const int o0 = (r + 32 * j0) * 8;             // ksub 0
    const int o1 = (r + 32 * (j0 ^ 2)) * 8;       // ksub 1

    f32x16 acc[4][2];
#pragma unroll
    for (int i = 0; i < 4; ++i)
#pragma unroll
        for (int j = 0; j < 2; ++j)
#pragma unroll
            for (int e = 0; e < 16; ++e) acc[i][j][e] = 0.f;

    auto stage = [&](int buf, int step) {
        int s  = s_begin + (step >> 3);
        int kq = step & 7;
        int ky = s / 9, kx = s - ky * 9;
        int aAdd = abase + (ky * 20 + kx) * 256 + kq * 32;
        int bAdd = bbase + s * 256 + kq * 32;
        f16* L = &lds[buf * 24576 + w * 1024];
        dma16(hh  + aAdd + c0 * 8, L);                 // Ah, b2=0
        dma16(hh  + aAdd + c1 * 8, L + 512);           // Ah, b2=1
        dma16(whT + bAdd + c0 * 8, L + 8192);          // Bh
        dma16(whT + bAdd + c1 * 8, L + 8192 + 512);
        dma16(wlT + bAdd + c0 * 8, L + 16384);         // Bl
        dma16(wlT + bAdd + c1 * 8, L + 16384 + 512);
    };

    stage(0, 0);
    __syncthreads();                              // buf0 visible to all waves

    for (int ts = 0; ts < nsteps; ++ts) {
        const int buf = ts & 1;
        if (ts + 1 < nsteps) stage(buf ^ 1, ts + 1);   // prefetch next step
        __builtin_amdgcn_sched_barrier(0);             // keep DMA issue early
        const f16* LA = &lds[buf * 24576 + wm * 4096];
        const f16* LB = &lds[buf * 24576 + 8192 + wn * 2048];
        __builtin_amdgcn_s_setprio(1);
#pragma unroll
        for (int ks = 0; ks < 2; ++ks) {
            const int o = ks ? o1 : o0;
            f16x8 ah[4], bh[2], bl[2];
#pragma unroll
            for (int mf = 0; mf < 4; ++mf)
                ah[mf] = *(const f16x8*)&LA[mf * 1024 + o];
#pragma unroll
            for (int nf = 0; nf < 2; ++nf) {
                bh[nf] = *(const f16x8*)&LB[nf * 1024 + o];
                bl[nf] = *(const f16x8*)&LB[8192 + nf * 1024 + o];
            }
            // term-outer order (distance-8 same-acc reuse)
#pragma unroll
            for (int mf = 0; mf < 4; ++mf)
#pragma unroll
                for (int nf = 0; nf < 2; ++nf)
                    acc[mf][nf] = __builtin_amdgcn_mfma_f32_32x32x16_f16(
                        ah[mf], bh[nf], acc[mf][nf], 0, 0, 0);
#pragma unroll
            for (int mf = 0; mf < 4; ++mf)
#pragma unroll
                for (int nf = 0; nf < 2; ++nf)
                    acc[mf][nf] = __builtin_amdgcn_mfma_f32_32x32x16_f16(
                        ah[mf], bl[nf], acc[mf][nf], 0, 0, 0);
        }
        __builtin_amdgcn_s_setprio(0);
        __syncthreads();                               // drains DMA + reads done
    }

    // epilogue: C/D 32x32 layout: col = lane&31, row = (reg&3)+8*(reg>>2)+4*half
    float bn[2];
#pragma unroll
    for (int nf = 0; nf < 2; ++nf) {
        int n = wn * 64 + nf * 32 + r;
        bn[nf] = (zi == 0) ? bias[n] : 0.f;
    }
#pragma unroll
    for (int mf = 0; mf < 4; ++mf) {
#pragma unroll
        for (int reg = 0; reg < 16; ++reg) {
            int row = (reg & 3) + 8 * (reg >> 2) + 4 * half;
            int mm  = m0 + wm * 128 + mf * 32 + row;
            int b2  = mm / 36, pix2 = mm - b2 * 36;
            size_t rowp = (size_t)(b_base + b2) * 9216 + pix2 * 8;
#pragma unroll
            for (int nf = 0; nf < 2; ++nf) {
                int n   = wn * 64 + nf * 32 + r;
                int cap = n >> 3, vec = n & 7;
                float v = acc[mf][nf][reg] * (1.0f / 2048.0f) + bn[nf];
                atomicAdd(&p[rowp + cap * 288 + vec], v);
            }
        }
    }
}

// ------------------------- dynamic routing (register-priors) ----------------
__global__ void __launch_bounds__(384) routing2(
    const float* __restrict__ p, const float* __restrict__ rw,
    float* __restrict__ caps)
{
    const int b = blockIdx.x;
    const int c = blockIdx.y;
    const int t = threadIdx.x;
    const int lane = t & 63, wid = t >> 6;
    __shared__ float redbuf[6];
    __shared__ float tred[6][16];
    __shared__ float outv[16];

    const float* pb  = p  + (size_t)b * 9216;
    const float* rwc = rw + (size_t)c * 147456;

    float q[3][16];
    float l[3] = {0.f, 0.f, 0.f};

#pragma unroll
    for (int j = 0; j < 3; ++j) {
        int r = t + 384 * j;
        float4 p0 = *(const float4*)&pb[r * 8];
        float4 p1 = *(const float4*)&pb[r * 8 + 4];
        float pr[8] = {p0.x, p0.y, p0.z, p0.w, p1.x, p1.y, p1.z, p1.w};
#pragma unroll
        for (int v = 0; v < 16; ++v) q[j][v] = 0.f;
        const float* wr = rwc + (size_t)r * 128;
#pragma unroll
        for (int i = 0; i < 8; ++i) {
#pragma unroll
            for (int v4 = 0; v4 < 4; ++v4) {
                float4 w4 = *(const float4*)&wr[i * 16 + v4 * 4];
                q[j][v4 * 4 + 0] = fmaf(pr[i], w4.x, q[j][v4 * 4 + 0]);
                q[j][v4 * 4 + 1] = fmaf(pr[i], w4.y, q[j][v4 * 4 + 1]);
                q[j][v4 * 4 + 2] = fmaf(pr[i], w4.z, q[j][v4 * 4 + 2]);
                q[j][v4 * 4 + 3] = fmaf(pr[i], w4.w, q[j][v4 * 4 + 3]);
            }
        }
    }

    for (int it = 0; it < 3; ++it) {
        float lm = fmaxf(fmaxf(l[0], l[1]), l[2]);
#pragma unroll
        for (int off = 32; off; off >>= 1) lm = fmaxf(lm, __shfl_down(lm, off, 64));
        __syncthreads();
        if (lane == 0) redbuf[wid] = lm;
        __syncthreads();
        lm = fmaxf(fmaxf(fmaxf(redbuf[0], redbuf[1]), fmaxf(redbuf[2], redbuf[3])),
                   fmaxf(redbuf[4], redbuf[5]));

        float e[3];
        float ls = 0.f;
#pragma unroll
        for (int j = 0; j < 3; ++j) { e[j] = __expf(l[j] - lm); ls += e[j]; }
#pragma unroll
        for (int off = 32; off; off >>= 1) ls += __shfl_down(ls, off, 64);
        __syncthreads();
        if (lane == 0) redbuf[wid] = ls;
        __syncthreads();
        ls = redbuf[0] + redbuf[1] + redbuf[2] + redbuf[3] + redbuf[4] + redbuf[5];
        const float inv = 1.f / ls;

        float tv[16];
#pragma unroll
        for (int v = 0; v < 16; ++v)
            tv[v] = fmaf(e[0], q[0][v], fmaf(e[1], q[1][v], e[2] * q[2][v]));
#pragma unroll
        for (int v = 0; v < 16; ++v) {
            float xv = tv[v];
#pragma unroll
            for (int off = 32; off; off >>= 1) xv += __shfl_down(xv, off, 64);
            tv[v] = xv;
        }
        __syncthreads();
        if (lane == 0) {
#pragma unroll
            for (int v = 0; v < 16; ++v) tred[wid][v] = tv[v];
        }
        __syncthreads();
        if (t < 16)
            outv[t] = (tred[0][t] + tred[1][t] + tred[2][t]
                     + tred[3][t] + tred[4][t] + tred[5][t]) * inv;
        __syncthreads();

        float s2 = 0.f;
#pragma unroll
        for (int v = 0; v < 16; ++v) s2 += outv[v] * outv[v];
        const float scale = s2 / ((1.f + s2) * sqrtf(s2));

        if (it == 2) {
            if (t < 16) caps[((size_t)b * 2 + c) * 16 + t] = scale * outv[t];
        } else {
            float ov[16];
#pragma unroll
            for (int v = 0; v < 16; ++v) ov[v] = scale * outv[v];
#pragma unroll
            for (int j = 0; j < 3; ++j) {
                float d = 0.f;
#pragma unroll
                for (int v = 0; v < 16; ++v) d = fmaf(q[j][v], ov[v], d);
                l[j] += d;
            }
        }
    }
}

// ------------------------- class softmax + argmax mask ----------------------
__global__ void __launch_bounds__(256) mask_kernel(
    const float* __restrict__ caps, float* __restrict__ cls_out,
    float* __restrict__ masked)
{
    int b = blockIdx.x * 256 + threadIdx.x;
    if (b < 1024) {
        const float* cb = caps + (size_t)b * 32;
        float n0 = 0.f, n1 = 0.f;
#pragma unroll
        for (int v = 0; v < 16; ++v) {
            n0 = fmaf(cb[v], cb[v], n0);
            n1 = fmaf(cb[16 + v], cb[16 + v], n1);
        }
        n0 = sqrtf(n0); n1 = sqrtf(n1);
        float mx = fmaxf(n0, n1);
        float e0 = expf(n0 - mx), e1 = expf(n1 - mx);
        float inv = 1.f / (e0 + e1);
        cls_out[b * 2 + 0] = e0 * inv;
        cls_out[b * 2 + 1] = e1 * inv;
        int cs = (n1 > n0) ? 1 : 0;
#pragma unroll
        for (int v = 0; v < 16; ++v) {
            masked[(size_t)b * 32 + v]      = (cs == 0) ? cb[v] : 0.f;
            masked[(size_t)b * 32 + 16 + v] = (cs == 1) ? cb[16 + v] : 0.f;
        }
    }
}

// ------------------------- decoder GEMM -------------------------------------
template<int ACT>
__global__ void __launch_bounds__(256) dense_gemm(
    const float* __restrict__ A, const float* __restrict__ Bw,
    const float* __restrict__ bias, float* __restrict__ out,
    int M, int N, int K)
{
    __shared__ __align__(16) float As[16][128];
    __shared__ __align__(16) float Bs[16][64];
    const int t  = threadIdx.x;
    const int m0 = blockIdx.x * 128, n0 = blockIdx.y * 64;
    const int tx = t & 15, ty = t >> 4;
    const int am = t >> 1;
    const int ak = (t & 1) * 8;
    const int nb = (t & 15) * 4, kb = t >> 4;

    float acc[8][4];
#pragma unroll
    for (int i = 0; i < 8; ++i)
#pragma unroll
        for (int j = 0; j < 4; ++j) acc[i][j] = 0.f;

    for (int k0i = 0; k0i < K; k0i += 16) {
        {
            const float* ap = A + (size_t)(m0 + am) * K + k0i + ak;
            float4 v0 = *(const float4*)ap;
            float4 v1 = *(const float4*)(ap + 4);
            As[ak + 0][am] = v0.x; As[ak + 1][am] = v0.y;
            As[ak + 2][am] = v0.z; As[ak + 3][am] = v0.w;
            As[ak + 4][am] = v1.x; As[ak + 5][am] = v1.y;
            As[ak + 6][am] = v1.z; As[ak + 7][am] = v1.w;
        }
        {
            int k = k0i + kb;
            int n = n0 + nb;
            float4 v4 = make_float4(0.f, 0.f, 0.f, 0.f);
            if (n + 3 < N) {
                v4 = *(const float4*)&Bw[(size_t)k * N + n];
            } else {
                float tmp[4] = {0.f, 0.f, 0.f, 0.f};
#pragma unroll
                for (int e = 0; e < 4; ++e)
                    if (n + e < N) tmp[e] = Bw[(size_t)k * N + n + e];
                v4 = make_float4(tmp[0], tmp[1], tmp[2], tmp[3]);
            }
            *(float4*)&Bs[kb][nb] = v4;
        }
        __syncthreads();
#pragma unroll
        for (int kk = 0; kk < 16; ++kk) {
            float4 a0 = *(const float4*)&As[kk][ty * 8];
            float4 a1 = *(const float4*)&As[kk][ty * 8 + 4];
            float4 b0 = *(const float4*)&Bs[kk][tx * 4];
            float av[8] = {a0.x, a0.y, a0.z, a0.w, a1.x, a1.y, a1.z, a1.w};
            float bv[4] = {b0.x, b0.y, b0.z, b0.w};
#pragma unroll
            for (int i = 0; i < 8; ++i)
#pragma unroll
                for (int j = 0; j < 4; ++j)
                    acc[i][j] = fmaf(av[i], bv[j], acc[i][j]);
        }
        __syncthreads();
    }
#pragma unroll
    for (int i = 0; i < 8; ++i) {
        int mm = m0 + ty * 8 + i;
#pragma unroll
        for (int j = 0; j < 4; ++j) {
            int n = n0 + tx * 4 + j;
            if (n < N) {
                float v = acc[i][j] + bias[n];
                v = (ACT == 0) ? fmaxf(v, 0.f) : 1.f / (1.f + expf(-v));
                out[(size_t)mm * N + n] = v;
            }
        }
    }
}

// ------------------------- host launcher ------------------------------------
extern "C" void kernel_launch(void* const* d_in, const int* in_sizes, int n_in,
                              void* d_out, int out_size, void* d_ws, size_t ws_size,
                              hipStream_t stream)
{
    const float* x       = (const float*)d_in[0];
    const float* conv1_w = (const float*)d_in[1];
    const float* conv1_b = (const float*)d_in[2];
    const float* prim_w  = (const float*)d_in[3];
    const float* prim_b  = (const float*)d_in[4];
    const float* route_w = (const float*)d_in[5];
    const float* dec_w1  = (const float*)d_in[6];
    const float* dec_b1  = (const float*)d_in[7];
    const float* dec_w2  = (const float*)d_in[8];
    const float* dec_b2  = (const float*)d_in[9];
    const float* dec_w3  = (const float*)d_in[10];
    const float* dec_b3  = (const float*)d_in[11];

    f16*   whT1 = (f16*)d_ws;                       //   65536 halves
    f16*   wlT1 = whT1 + 65536;
    f16*   whT  = wlT1 + 65536;                     // 5308416 halves
    f16*   wlT  = whT + 5308416;
    float* pbuf   = (float*)(wlT + 5308416);        // 9437184 f32
    float* caps   = pbuf + 9437184;
    float* masked = caps + 32768;
    float* d1     = masked + 32768;
    float* d2     = d1 + 524288;
    f16*   hbase  = (f16*)(d2 + 1048576);
    float* outF   = (float*)d_out;

    const size_t fixed_bytes = 65798144ull;
    int chunk = 64;
    const int cand[4] = {512, 256, 128, 64};
    for (int i = 0; i < 4; ++i) {
        if (fixed_bytes + (size_t)cand[i] * 204800ull <= ws_size) {
            chunk = cand[i];
            break;
        }
    }
    if (chunk > 256) chunk = 256;                   // hh sized per chunk
    f16* hh = hbase;

    // p accumulated via atomics (split-K) -> zero it
    hipMemsetAsync(pbuf, 0, 9437184ull * sizeof(float), stream);

    w1split<<<256, 256, 0, stream>>>(conv1_w, whT1, wlT1);
    transpose_split_w<<<dim3(256, 4), 256, 0, stream>>>(prim_w, whT, wlT);

    const int nchunks = 1024 / chunk;
    for (int ci = 0; ci < nchunks; ++ci) {
        const float* xin = x + (size_t)ci * chunk * 2352;
        conv1_mfma<<<dim3(chunk * 400 / 64, 4), 256, 0, stream>>>(
            xin, whT1, wlT1, conv1_b, hh);
        prim_mfma256<<<dim3(chunk * 36 / 256, 7), 512, 0, stream>>>(
            hh, whT, wlT, prim_b, pbuf, ci * chunk);
    }

    routing2<<<dim3(1024, 2), 384, 0, stream>>>(pbuf, route_w, caps);
    mask_kernel<<<4, 256, 0, stream>>>(caps, outF, masked);

    dense_gemm<0><<<dim3(8, 8),  256, 0, stream>>>(masked, dec_w1, dec_b1, d1, 1024, 512, 32);
    dense_gemm<0><<<dim3(8, 16), 256, 0, stream>>>(d1, dec_w2, dec_b2, d2, 1024, 1024, 512);
    dense_gemm<1><<<dim3(8, 13), 256, 0, stream>>>(d2, dec_w3, dec_b3, outF + 2048, 1024, 784, 1024);
}

// Round 6
// 1623.945 us; speedup vs baseline: 6.6153x; 1.1851x over previous
//
#include <hip/hip_runtime.h>
#include <hip/hip_bf16.h>
#include <cmath>
#include <cstdint>

// ---------------------------------------------------------------------------
// CapsuleNet forward. Round 11 (= R10 structure, B-residual path DELETED):
//   - Numerics: pure-f16 MFMA GEMMs. prim: C = f16(16A) * f16(128W) / 2048.
//     A-f16 (R10) and W-f16 (this round) each carry rel err 2^-12; R10
//     measured absmax unchanged under A-f16, and W-f16 is symmetric
//     (~2e-4 abs on priors with std ~0.9, 20x under the 0.0039 floor).
//   - prim: 256x256 block, 8 waves (2x4) of 128x64 (acc[4][2]), K-step 32,
//     double-buffered 64 KiB LDS {Ah,Bh}, 4 dma16/step/wave, split-K z=7,
//     __syncthreads pipeline (measured best), single MFMA product.
//   - conv1: pure f16(x)*f16(w1); no residual anywhere.
//   - weight prep emits hi-parts only.
// ---------------------------------------------------------------------------

typedef _Float16 f16;
typedef _Float16 f16x8 __attribute__((ext_vector_type(8)));
typedef float    f32x4 __attribute__((ext_vector_type(4)));
typedef float    f32x16 __attribute__((ext_vector_type(16)));

__device__ __forceinline__ void dma16(const f16* g, f16* l)
{
    __builtin_amdgcn_global_load_lds(
        (const __attribute__((address_space(1))) void*)g,
        (__attribute__((address_space(3))) void*)l, 16, 0, 0);
}

// ------------------------- conv1 weight: [n][k], k = c*81+khw ---------------
__global__ void __launch_bounds__(256) w1prep(
    const float* __restrict__ w, f16* __restrict__ wh)
{
    int idx = blockIdx.x * 256 + threadIdx.x;       // 65536
    int n = idx >> 8, k = idx & 255;
    float v = (k < 243) ? w[n * 243 + k] : 0.f;
    wh[idx] = (f16)v;
}

// ------------------------- prim weight: permute to [n][khw*256+c], x128 -----
__global__ void __launch_bounds__(256) transpose_w(
    const float* __restrict__ w, f16* __restrict__ whT)
{
    __shared__ float tile[5184];                  // 64 c x 81 khw
    const int n  = blockIdx.x;                    // 0..255
    const int cq = blockIdx.y;                    // 0..3
    const int t  = threadIdx.x;
    const float* wr = w + (size_t)n * 20736 + cq * 5184;
    for (int i = t; i < 5184; i += 256) tile[i] = wr[i];
    __syncthreads();
    f16* oh = whT + (size_t)n * 20736 + cq * 64;
    for (int idx = t; idx < 648; idx += 256) {    // 81 khw x 8 c-groups
        int khw = idx >> 3, cg = idx & 7;
        f16x8 vh;
#pragma unroll
        for (int e = 0; e < 8; ++e)
            vh[e] = (f16)(tile[(cg * 8 + e) * 81 + khw] * 128.0f);
        *(f16x8*)&oh[khw * 256 + cg * 8] = vh;
    }
}

// ------------------------- conv1: fused im2col + f16 MFMA -------------------
// C[M=chunk*400, 256] = im2col(x)[M,256] * W1[256,256]; bias+ReLU;
// output stored as hh = f16(16*v).
__global__ void __launch_bounds__(256) conv1_mfma(
    const float* __restrict__ x,
    const f16* __restrict__ wh,
    const float* __restrict__ bias, f16* __restrict__ hh)
{
    __shared__ __align__(16) f16 Ah[4096], Bh[4096];
    __shared__ int otab[256];
    const int t  = threadIdx.x;
    const int m0 = blockIdx.x * 64;
    const int n0 = blockIdx.y * 64;

    {   // otab: k -> x offset (c*784 + ky*28 + kx), -1 pads
        int k = t;
        int off = -1;
        if (k < 243) {
            int c = k / 81, khw = k - c * 81;
            int ky = khw / 9, kx = khw - ky * 9;
            off = c * 784 + ky * 28 + kx;
        }
        otab[t] = off;
    }

    const int sr = t >> 3;
    const int sg = t & 7;
    const float* xb[2];
    int bbase[2], wofs[2];
#pragma unroll
    for (int pp = 0; pp < 2; ++pp) {
        int r = pp * 32 + sr;
        int m = m0 + r;
        int bb = m / 400, pix = m - bb * 400;
        int py = pix / 20, px = pix - py * 20;
        xb[pp] = x + (size_t)bb * 2352 + py * 28 + px;
        bbase[pp] = (n0 + r) * 256 + sg * 8;
        wofs[pp] = r * 64 + ((sg ^ (r & 7)) * 8);
    }

    float rx[2][8];
    f16x8 rBh[2];
    __syncthreads();                              // otab ready
    auto stage = [&](int s) {
#pragma unroll
        for (int pp = 0; pp < 2; ++pp) {
#pragma unroll
            for (int e = 0; e < 8; ++e) {
                int off = otab[s * 64 + sg * 8 + e];
                rx[pp][e] = (off >= 0) ? xb[pp][off] : 0.f;
            }
            rBh[pp] = *(const f16x8*)&wh[bbase[pp] + s * 64];
        }
    };

    const int lane = t & 63;
    const int wv   = t >> 6;
    const int wm   = wv >> 1, wn = wv & 1;
    const int li   = lane & 15, lq = lane >> 4;

    f32x4 acc_h[2][2];
#pragma unroll
    for (int i = 0; i < 2; ++i)
#pragma unroll
        for (int j = 0; j < 2; ++j)
            acc_h[i][j] = (f32x4){0.f, 0.f, 0.f, 0.f};

    stage(0);

    for (int s = 0; s < 4; ++s) {
        __syncthreads();
#pragma unroll
        for (int pp = 0; pp < 2; ++pp) {
            f16x8 vh;
#pragma unroll
            for (int e = 0; e < 8; ++e) vh[e] = (f16)rx[pp][e];
            *(f16x8*)&Ah[wofs[pp]] = vh;
            *(f16x8*)&Bh[wofs[pp]] = rBh[pp];
        }
        __syncthreads();
        if (s + 1 < 4) stage(s + 1);
#pragma unroll
        for (int h = 0; h < 2; ++h) {
            int g = h * 4 + lq;
            f16x8 ah[2], bh[2];
#pragma unroll
            for (int mf = 0; mf < 2; ++mf) {
                int r = wm * 32 + mf * 16 + li;
                int u = r * 64 + ((g ^ (r & 7)) * 8);
                ah[mf] = *(const f16x8*)&Ah[u];
            }
#pragma unroll
            for (int nf = 0; nf < 2; ++nf) {
                int r = wn * 32 + nf * 16 + li;
                int u = r * 64 + ((g ^ (r & 7)) * 8);
                bh[nf] = *(const f16x8*)&Bh[u];
            }
#pragma unroll
            for (int mf = 0; mf < 2; ++mf)
#pragma unroll
                for (int nf = 0; nf < 2; ++nf)
                    acc_h[mf][nf] = __builtin_amdgcn_mfma_f32_16x16x32_f16(
                        ah[mf], bh[nf], acc_h[mf][nf], 0, 0, 0);
        }
    }

    float bn[2];
    bn[0] = bias[n0 + wn * 32 + li];
    bn[1] = bias[n0 + wn * 32 + 16 + li];
#pragma unroll
    for (int mf = 0; mf < 2; ++mf) {
        int mb = m0 + wm * 32 + mf * 16 + lq * 4;
#pragma unroll
        for (int r = 0; r < 4; ++r) {
            size_t row = (size_t)(mb + r) * 256;
#pragma unroll
            for (int nf = 0; nf < 2; ++nf) {
                int n   = n0 + wn * 32 + nf * 16 + li;
                float v = acc_h[mf][nf][r] + bn[nf];
                v = fmaxf(v, 0.f) * 16.0f;        // x16 scale for prim A-side
                hh[row + n] = (f16)v;
            }
        }
    }
}

// ------------------------- prim conv: 256x256 block, pure f16, dbuf ---------
// GEMM: C[M=chunk*36, 256] += im2col(h16)[M,Kz] * W128[Kz,256], summed over
// z=7 spatial-tap ranges. acc = (16A)(128W) = 2048*C; epilogue /2048.
// LDS per buffer (16384 f16 = 32 KiB): Ah[0..8191] Bh[+8192],
// each 8 chunks x (32 rows x 32 k f16).
// Slot swizzle within a 2KB chunk: slot(r,c) = r + 32*((c+r)&3), c = ks*2+half
// -> frag reads (fixed c, r=lane&31) conflict-free. global_load_lds writes
// linearly; inverse perm applied on per-lane global source column c0/c1.
// Pipeline: {stage(next); compute(cur); __syncthreads} (measured best).
__global__ void __launch_bounds__(512, 2) prim_mfma256(
    const f16* __restrict__ hh,
    const f16* __restrict__ whT,
    const float* __restrict__ bias, float* __restrict__ p, int b_base)
{
    __shared__ __align__(16) f16 lds[32768];      // 64 KiB, 2 buffers a 16384
    const int t  = threadIdx.x;
    const int m0 = blockIdx.x * 256;
    const int zi = blockIdx.y;                    // 0..6
    const int s_begin = (zi < 4) ? zi * 12 : 48 + (zi - 4) * 11;
    const int s_cnt   = (zi < 4) ? 12 : 11;
    const int nsteps  = s_cnt * 8;                // K-steps of 32 channels

    const int l  = t & 63, w = t >> 6;            // wave 0..7
    const int wm = w >> 2, wn = w & 3;            // 2 x 4 wave grid
    const int r  = l & 31, half = l >> 5;

    // ---- staging lane constants: wave w stages A-chunk w and B-chunk w ----
    int m  = m0 + 32 * w + r;
    int bb = m / 36, pix = m - bb * 36;
    int py = pix / 6, px = pix - py * 6;
    const int abase = (bb * 400 + py * 40 + px * 2) * 256;   // f16 idx in hh
    const int bbase = (32 * w + r) * 20736;                  // f16 idx in whT
    const int c0 = (half - (r & 3)) & 3;          // slot-col for b2 = 0
    const int c1 = (c0 + 2) & 3;                  // slot-col for b2 = 1

    // ---- frag-read lane offsets (f16 units within 1024-f16 chunk) ----
    const int j0 = (half + r) & 3;
    const int o0 = (r + 32 * j0) * 8;             // ksub 0
    const int o1 = (r + 32 * (j0 ^ 2)) * 8;       // ksub 1

    f32x16 acc[4][2];
#pragma unroll
    for (int i = 0; i < 4; ++i)
#pragma unroll
        for (int j = 0; j < 2; ++j)
#pragma unroll
            for (int e = 0; e < 16; ++e) acc[i][j][e] = 0.f;

    auto stage = [&](int buf, int step) {
        int s  = s_begin + (step >> 3);
        int kq = step & 7;
        int ky = s / 9, kx = s - ky * 9;
        int aAdd = abase + (ky * 20 + kx) * 256 + kq * 32;
        int bAdd = bbase + s * 256 + kq * 32;
        f16* L = &lds[buf * 16384 + w * 1024];
        dma16(hh  + aAdd + c0 * 8, L);                 // Ah, b2=0
        dma16(hh  + aAdd + c1 * 8, L + 512);           // Ah, b2=1
        dma16(whT + bAdd + c0 * 8, L + 8192);          // Bh
        dma16(whT + bAdd + c1 * 8, L + 8192 + 512);
    };

    stage(0, 0);
    __syncthreads();                              // buf0 visible to all waves

    for (int ts = 0; ts < nsteps; ++ts) {
        const int buf = ts & 1;
        if (ts + 1 < nsteps) stage(buf ^ 1, ts + 1);   // prefetch next step
        __builtin_amdgcn_sched_barrier(0);             // keep DMA issue early
        const f16* LA = &lds[buf * 16384 + wm * 4096];
        const f16* LB = &lds[buf * 16384 + 8192 + wn * 2048];
        __builtin_amdgcn_s_setprio(1);
#pragma unroll
        for (int ks = 0; ks < 2; ++ks) {
            const int o = ks ? o1 : o0;
            f16x8 ah[4], bh[2];
#pragma unroll
            for (int mf = 0; mf < 4; ++mf)
                ah[mf] = *(const f16x8*)&LA[mf * 1024 + o];
#pragma unroll
            for (int nf = 0; nf < 2; ++nf)
                bh[nf] = *(const f16x8*)&LB[nf * 1024 + o];
#pragma unroll
            for (int mf = 0; mf < 4; ++mf)
#pragma unroll
                for (int nf = 0; nf < 2; ++nf)
                    acc[mf][nf] = __builtin_amdgcn_mfma_f32_32x32x16_f16(
                        ah[mf], bh[nf], acc[mf][nf], 0, 0, 0);
        }
        __builtin_amdgcn_s_setprio(0);
        __syncthreads();                               // drains DMA + reads done
    }

    // epilogue: C/D 32x32 layout: col = lane&31, row = (reg&3)+8*(reg>>2)+4*half
    float bn[2];
#pragma unroll
    for (int nf = 0; nf < 2; ++nf) {
        int n = wn * 64 + nf * 32 + r;
        bn[nf] = (zi == 0) ? bias[n] : 0.f;
    }
#pragma unroll
    for (int mf = 0; mf < 4; ++mf) {
#pragma unroll
        for (int reg = 0; reg < 16; ++reg) {
            int row = (reg & 3) + 8 * (reg >> 2) + 4 * half;
            int mm  = m0 + wm * 128 + mf * 32 + row;
            int b2  = mm / 36, pix2 = mm - b2 * 36;
            size_t rowp = (size_t)(b_base + b2) * 9216 + pix2 * 8;
#pragma unroll
            for (int nf = 0; nf < 2; ++nf) {
                int n   = wn * 64 + nf * 32 + r;
                int cap = n >> 3, vec = n & 7;
                float v = acc[mf][nf][reg] * (1.0f / 2048.0f) + bn[nf];
                atomicAdd(&p[rowp + cap * 288 + vec], v);
            }
        }
    }
}

// ------------------------- dynamic routing (register-priors) ----------------
__global__ void __launch_bounds__(384) routing2(
    const float* __restrict__ p, const float* __restrict__ rw,
    float* __restrict__ caps)
{
    const int b = blockIdx.x;
    const int c = blockIdx.y;
    const int t = threadIdx.x;
    const int lane = t & 63, wid = t >> 6;
    __shared__ float redbuf[6];
    __shared__ float tred[6][16];
    __shared__ float outv[16];

    const float* pb  = p  + (size_t)b * 9216;
    const float* rwc = rw + (size_t)c * 147456;

    float q[3][16];
    float l[3] = {0.f, 0.f, 0.f};

#pragma unroll
    for (int j = 0; j < 3; ++j) {
        int r = t + 384 * j;
        float4 p0 = *(const float4*)&pb[r * 8];
        float4 p1 = *(const float4*)&pb[r * 8 + 4];
        float pr[8] = {p0.x, p0.y, p0.z, p0.w, p1.x, p1.y, p1.z, p1.w};
#pragma unroll
        for (int v = 0; v < 16; ++v) q[j][v] = 0.f;
        const float* wr = rwc + (size_t)r * 128;
#pragma unroll
        for (int i = 0; i < 8; ++i) {
#pragma unroll
            for (int v4 = 0; v4 < 4; ++v4) {
                float4 w4 = *(const float4*)&wr[i * 16 + v4 * 4];
                q[j][v4 * 4 + 0] = fmaf(pr[i], w4.x, q[j][v4 * 4 + 0]);
                q[j][v4 * 4 + 1] = fmaf(pr[i], w4.y, q[j][v4 * 4 + 1]);
                q[j][v4 * 4 + 2] = fmaf(pr[i], w4.z, q[j][v4 * 4 + 2]);
                q[j][v4 * 4 + 3] = fmaf(pr[i], w4.w, q[j][v4 * 4 + 3]);
            }
        }
    }

    for (int it = 0; it < 3; ++it) {
        float lm = fmaxf(fmaxf(l[0], l[1]), l[2]);
#pragma unroll
        for (int off = 32; off; off >>= 1) lm = fmaxf(lm, __shfl_down(lm, off, 64));
        __syncthreads();
        if (lane == 0) redbuf[wid] = lm;
        __syncthreads();
        lm = fmaxf(fmaxf(fmaxf(redbuf[0], redbuf[1]), fmaxf(redbuf[2], redbuf[3])),
                   fmaxf(redbuf[4], redbuf[5]));

        float e[3];
        float ls = 0.f;
#pragma unroll
        for (int j = 0; j < 3; ++j) { e[j] = __expf(l[j] - lm); ls += e[j]; }
#pragma unroll
        for (int off = 32; off; off >>= 1) ls += __shfl_down(ls, off, 64);
        __syncthreads();
        if (lane == 0) redbuf[wid] = ls;
        __syncthreads();
        ls = redbuf[0] + redbuf[1] + redbuf[2] + redbuf[3] + redbuf[4] + redbuf[5];
        const float inv = 1.f / ls;

        float tv[16];
#pragma unroll
        for (int v = 0; v < 16; ++v)
            tv[v] = fmaf(e[0], q[0][v], fmaf(e[1], q[1][v], e[2] * q[2][v]));
#pragma unroll
        for (int v = 0; v < 16; ++v) {
            float xv = tv[v];
#pragma unroll
            for (int off = 32; off; off >>= 1) xv += __shfl_down(xv, off, 64);
            tv[v] = xv;
        }
        __syncthreads();
        if (lane == 0) {
#pragma unroll
            for (int v = 0; v < 16; ++v) tred[wid][v] = tv[v];
        }
        __syncthreads();
        if (t < 16)
            outv[t] = (tred[0][t] + tred[1][t] + tred[2][t]
                     + tred[3][t] + tred[4][t] + tred[5][t]) * inv;
        __syncthreads();

        float s2 = 0.f;
#pragma unroll
        for (int v = 0; v < 16; ++v) s2 += outv[v] * outv[v];
        const float scale = s2 / ((1.f + s2) * sqrtf(s2));

        if (it == 2) {
            if (t < 16) caps[((size_t)b * 2 + c) * 16 + t] = scale * outv[t];
        } else {
            float ov[16];
#pragma unroll
            for (int v = 0; v < 16; ++v) ov[v] = scale * outv[v];
#pragma unroll
            for (int j = 0; j < 3; ++j) {
                float d = 0.f;
#pragma unroll
                for (int v = 0; v < 16; ++v) d = fmaf(q[j][v], ov[v], d);
                l[j] += d;
            }
        }
    }
}

// ------------------------- class softmax + argmax mask ----------------------
__global__ void __launch_bounds__(256) mask_kernel(
    const float* __restrict__ caps, float* __restrict__ cls_out,
    float* __restrict__ masked)
{
    int b = blockIdx.x * 256 + threadIdx.x;
    if (b < 1024) {
        const float* cb = caps + (size_t)b * 32;
        float n0 = 0.f, n1 = 0.f;
#pragma unroll
        for (int v = 0; v < 16; ++v) {
            n0 = fmaf(cb[v], cb[v], n0);
            n1 = fmaf(cb[16 + v], cb[16 + v], n1);
        }
        n0 = sqrtf(n0); n1 = sqrtf(n1);
        float mx = fmaxf(n0, n1);
        float e0 = expf(n0 - mx), e1 = expf(n1 - mx);
        float inv = 1.f / (e0 + e1);
        cls_out[b * 2 + 0] = e0 * inv;
        cls_out[b * 2 + 1] = e1 * inv;
        int cs = (n1 > n0) ? 1 : 0;
#pragma unroll
        for (int v = 0; v < 16; ++v) {
            masked[(size_t)b * 32 + v]      = (cs == 0) ? cb[v] : 0.f;
            masked[(size_t)b * 32 + 16 + v] = (cs == 1) ? cb[16 + v] : 0.f;
        }
    }
}

// ------------------------- decoder GEMM -------------------------------------
template<int ACT>
__global__ void __launch_bounds__(256) dense_gemm(
    const float* __restrict__ A, const float* __restrict__ Bw,
    const float* __restrict__ bias, float* __restrict__ out,
    int M, int N, int K)
{
    __shared__ __align__(16) float As[16][128];
    __shared__ __align__(16) float Bs[16][64];
    const int t  = threadIdx.x;
    const int m0 = blockIdx.x * 128, n0 = blockIdx.y * 64;
    const int tx = t & 15, ty = t >> 4;
    const int am = t >> 1;
    const int ak = (t & 1) * 8;
    const int nb = (t & 15) * 4, kb = t >> 4;

    float acc[8][4];
#pragma unroll
    for (int i = 0; i < 8; ++i)
#pragma unroll
        for (int j = 0; j < 4; ++j) acc[i][j] = 0.f;

    for (int k0i = 0; k0i < K; k0i += 16) {
        {
            const float* ap = A + (size_t)(m0 + am) * K + k0i + ak;
            float4 v0 = *(const float4*)ap;
            float4 v1 = *(const float4*)(ap + 4);
            As[ak + 0][am] = v0.x; As[ak + 1][am] = v0.y;
            As[ak + 2][am] = v0.z; As[ak + 3][am] = v0.w;
            As[ak + 4][am] = v1.x; As[ak + 5][am] = v1.y;
            As[ak + 6][am] = v1.z; As[ak + 7][am] = v1.w;
        }
        {
            int k = k0i + kb;
            int n = n0 + nb;
            float4 v4 = make_float4(0.f, 0.f, 0.f, 0.f);
            if (n + 3 < N) {
                v4 = *(const float4*)&Bw[(size_t)k * N + n];
            } else {
                float tmp[4] = {0.f, 0.f, 0.f, 0.f};
#pragma unroll
                for (int e = 0; e < 4; ++e)
                    if (n + e < N) tmp[e] = Bw[(size_t)k * N + n + e];
                v4 = make_float4(tmp[0], tmp[1], tmp[2], tmp[3]);
            }
            *(float4*)&Bs[kb][nb] = v4;
        }
        __syncthreads();
#pragma unroll
        for (int kk = 0; kk < 16; ++kk) {
            float4 a0 = *(const float4*)&As[kk][ty * 8];
            float4 a1 = *(const float4*)&As[kk][ty * 8 + 4];
            float4 b0 = *(const float4*)&Bs[kk][tx * 4];
            float av[8] = {a0.x, a0.y, a0.z, a0.w, a1.x, a1.y, a1.z, a1.w};
            float bv[4] = {b0.x, b0.y, b0.z, b0.w};
#pragma unroll
            for (int i = 0; i < 8; ++i)
#pragma unroll
                for (int j = 0; j < 4; ++j)
                    acc[i][j] = fmaf(av[i], bv[j], acc[i][j]);
        }
        __syncthreads();
    }
#pragma unroll
    for (int i = 0; i < 8; ++i) {
        int mm = m0 + ty * 8 + i;
#pragma unroll
        for (int j = 0; j < 4; ++j) {
            int n = n0 + tx * 4 + j;
            if (n < N) {
                float v = acc[i][j] + bias[n];
                v = (ACT == 0) ? fmaxf(v, 0.f) : 1.f / (1.f + expf(-v));
                out[(size_t)mm * N + n] = v;
            }
        }
    }
}

// ------------------------- host launcher ------------------------------------
extern "C" void kernel_launch(void* const* d_in, const int* in_sizes, int n_in,
                              void* d_out, int out_size, void* d_ws, size_t ws_size,
                              hipStream_t stream)
{
    const float* x       = (const float*)d_in[0];
    const float* conv1_w = (const float*)d_in[1];
    const float* conv1_b = (const float*)d_in[2];
    const float* prim_w  = (const float*)d_in[3];
    const float* prim_b  = (const float*)d_in[4];
    const float* route_w = (const float*)d_in[5];
    const float* dec_w1  = (const float*)d_in[6];
    const float* dec_b1  = (const float*)d_in[7];
    const float* dec_w2  = (const float*)d_in[8];
    const float* dec_b2  = (const float*)d_in[9];
    const float* dec_w3  = (const float*)d_in[10];
    const float* dec_b3  = (const float*)d_in[11];

    f16*   whT1 = (f16*)d_ws;                       //   65536 halves
    f16*   whT  = whT1 + 65536;                     // 5308416 halves
    float* pbuf   = (float*)(whT + 5308416);        // 9437184 f32
    float* caps   = pbuf + 9437184;
    float* masked = caps + 32768;
    float* d1     = masked + 32768;
    float* d2     = d1 + 524288;
    f16*   hbase  = (f16*)(d2 + 1048576);
    float* outF   = (float*)d_out;

    const size_t fixed_bytes = 55050240ull;
    int chunk = 64;
    const int cand[4] = {512, 256, 128, 64};
    for (int i = 0; i < 4; ++i) {
        if (fixed_bytes + (size_t)cand[i] * 204800ull <= ws_size) {
            chunk = cand[i];
            break;
        }
    }
    if (chunk > 256) chunk = 256;                   // hh sized per chunk
    f16* hh = hbase;

    // p accumulated via atomics (split-K) -> zero it
    hipMemsetAsync(pbuf, 0, 9437184ull * sizeof(float), stream);

    w1prep<<<256, 256, 0, stream>>>(conv1_w, whT1);
    transpose_w<<<dim3(256, 4), 256, 0, stream>>>(prim_w, whT);

    const int nchunks = 1024 / chunk;
    for (int ci = 0; ci < nchunks; ++ci) {
        const float* xin = x + (size_t)ci * chunk * 2352;
        conv1_mfma<<<dim3(chunk * 400 / 64, 4), 256, 0, stream>>>(
            xin, whT1, conv1_b, hh);
        prim_mfma256<<<dim3(chunk * 36 / 256, 7), 512, 0, stream>>>(
            hh, whT, prim_b, pbuf, ci * chunk);
    }

    routing2<<<dim3(1024, 2), 384, 0, stream>>>(pbuf, route_w, caps);
    mask_kernel<<<4, 256, 0, stream>>>(caps, outF, masked);

    dense_gemm<0><<<dim3(8, 8),  256, 0, stream>>>(masked, dec_w1, dec_b1, d1, 1024, 512, 32);
    dense_gemm<0><<<dim3(8, 16), 256, 0, stream>>>(d1, dec_w2, dec_b2, d2, 1024, 1024, 512);
    dense_gemm<1><<<dim3(8, 13), 256, 0, stream>>>(d2, dec_w3, dec_b3, outF + 2048, 1024, 784, 1024);
}

// Round 7
// 1509.068 us; speedup vs baseline: 7.1189x; 1.0761x over previous
//
#include <hip/hip_runtime.h>
#include <hip/hip_bf16.h>
#include <cmath>
#include <cstdint>

// ---------------------------------------------------------------------------
// CapsuleNet forward. Round 12 (= R11 + routing coalescing + prim BK=64):
//   - routing2: route_w pre-transposed to rwT[c][i][r][v] so the q-load is
//     lane-coalesced (was: per-thread 512-B rows -> 8x L1 line inflation,
//     measured 244 us with all pipes idle).
//   - prim: K-step 32 -> 64 (48 steps instead of 96; per-step fixed overhead
//     ~3700 cyc amortized over 2x MFMA work). LDS dbuf 128 KiB (1 block/CU,
//     which grid 252<=256 already forced). 8 dma16/wave/step, 128-B global
//     segments. XOR slot swizzle (r,e) holds logical col e^(r&7); write-side
//     perm applied on global source col, read-side on ds_read addr.
//     k-order unchanged -> bit-identical accumulation.
//   - Numerics: pure-f16 MFMA GEMMs (R11), acc = 2048*C, epilogue /2048.
// ---------------------------------------------------------------------------

typedef _Float16 f16;
typedef _Float16 f16x8 __attribute__((ext_vector_type(8)));
typedef float    f32x4 __attribute__((ext_vector_type(4)));
typedef float    f32x16 __attribute__((ext_vector_type(16)));

__device__ __forceinline__ void dma16(const f16* g, f16* l)
{
    __builtin_amdgcn_global_load_lds(
        (const __attribute__((address_space(1))) void*)g,
        (__attribute__((address_space(3))) void*)l, 16, 0, 0);
}

// ------------------------- conv1 weight: [n][k], k = c*81+khw ---------------
__global__ void __launch_bounds__(256) w1prep(
    const float* __restrict__ w, f16* __restrict__ wh)
{
    int idx = blockIdx.x * 256 + threadIdx.x;       // 65536
    int n = idx >> 8, k = idx & 255;
    float v = (k < 243) ? w[n * 243 + k] : 0.f;
    wh[idx] = (f16)v;
}

// ------------------------- prim weight: permute to [n][khw*256+c], x128 -----
__global__ void __launch_bounds__(256) transpose_w(
    const float* __restrict__ w, f16* __restrict__ whT)
{
    __shared__ float tile[5184];                  // 64 c x 81 khw
    const int n  = blockIdx.x;                    // 0..255
    const int cq = blockIdx.y;                    // 0..3
    const int t  = threadIdx.x;
    const float* wr = w + (size_t)n * 20736 + cq * 5184;
    for (int i = t; i < 5184; i += 256) tile[i] = wr[i];
    __syncthreads();
    f16* oh = whT + (size_t)n * 20736 + cq * 64;
    for (int idx = t; idx < 648; idx += 256) {    // 81 khw x 8 c-groups
        int khw = idx >> 3, cg = idx & 7;
        f16x8 vh;
#pragma unroll
        for (int e = 0; e < 8; ++e)
            vh[e] = (f16)(tile[(cg * 8 + e) * 81 + khw] * 128.0f);
        *(f16x8*)&oh[khw * 256 + cg * 8] = vh;
    }
}

// ------------------------- route_w transpose: [c][r][i][v] -> [c][i][r][v] --
__global__ void __launch_bounds__(128) transpose_rw(
    const float* __restrict__ rw, float* __restrict__ rwT)
{
    const int r = blockIdx.x;                     // 0..1151
    const int c = blockIdx.y;                     // 0..1
    const int t = threadIdx.x;                    // 128
    const int i = t >> 4, v = t & 15;
    float val = rw[(((size_t)c * 1152 + r) * 8 + i) * 16 + v];
    rwT[(((size_t)c * 8 + i) * 1152 + r) * 16 + v] = val;
}

// ------------------------- conv1: fused im2col + f16 MFMA -------------------
// C[M=chunk*400, 256] = im2col(x)[M,256] * W1[256,256]; bias+ReLU;
// output stored as hh = f16(16*v).
__global__ void __launch_bounds__(256) conv1_mfma(
    const float* __restrict__ x,
    const f16* __restrict__ wh,
    const float* __restrict__ bias, f16* __restrict__ hh)
{
    __shared__ __align__(16) f16 Ah[4096], Bh[4096];
    __shared__ int otab[256];
    const int t  = threadIdx.x;
    const int m0 = blockIdx.x * 64;
    const int n0 = blockIdx.y * 64;

    {   // otab: k -> x offset (c*784 + ky*28 + kx), -1 pads
        int k = t;
        int off = -1;
        if (k < 243) {
            int c = k / 81, khw = k - c * 81;
            int ky = khw / 9, kx = khw - ky * 9;
            off = c * 784 + ky * 28 + kx;
        }
        otab[t] = off;
    }

    const int sr = t >> 3;
    const int sg = t & 7;
    const float* xb[2];
    int bbase[2], wofs[2];
#pragma unroll
    for (int pp = 0; pp < 2; ++pp) {
        int r = pp * 32 + sr;
        int m = m0 + r;
        int bb = m / 400, pix = m - bb * 400;
        int py = pix / 20, px = pix - py * 20;
        xb[pp] = x + (size_t)bb * 2352 + py * 28 + px;
        bbase[pp] = (n0 + r) * 256 + sg * 8;
        wofs[pp] = r * 64 + ((sg ^ (r & 7)) * 8);
    }

    float rx[2][8];
    f16x8 rBh[2];
    __syncthreads();                              // otab ready
    auto stage = [&](int s) {
#pragma unroll
        for (int pp = 0; pp < 2; ++pp) {
#pragma unroll
            for (int e = 0; e < 8; ++e) {
                int off = otab[s * 64 + sg * 8 + e];
                rx[pp][e] = (off >= 0) ? xb[pp][off] : 0.f;
            }
            rBh[pp] = *(const f16x8*)&wh[bbase[pp] + s * 64];
        }
    };

    const int lane = t & 63;
    const int wv   = t >> 6;
    const int wm   = wv >> 1, wn = wv & 1;
    const int li   = lane & 15, lq = lane >> 4;

    f32x4 acc_h[2][2];
#pragma unroll
    for (int i = 0; i < 2; ++i)
#pragma unroll
        for (int j = 0; j < 2; ++j)
            acc_h[i][j] = (f32x4){0.f, 0.f, 0.f, 0.f};

    stage(0);

    for (int s = 0; s < 4; ++s) {
        __syncthreads();
#pragma unroll
        for (int pp = 0; pp < 2; ++pp) {
            f16x8 vh;
#pragma unroll
            for (int e = 0; e < 8; ++e) vh[e] = (f16)rx[pp][e];
            *(f16x8*)&Ah[wofs[pp]] = vh;
            *(f16x8*)&Bh[wofs[pp]] = rBh[pp];
        }
        __syncthreads();
        if (s + 1 < 4) stage(s + 1);
#pragma unroll
        for (int h = 0; h < 2; ++h) {
            int g = h * 4 + lq;
            f16x8 ah[2], bh[2];
#pragma unroll
            for (int mf = 0; mf < 2; ++mf) {
                int r = wm * 32 + mf * 16 + li;
                int u = r * 64 + ((g ^ (r & 7)) * 8);
                ah[mf] = *(const f16x8*)&Ah[u];
            }
#pragma unroll
            for (int nf = 0; nf < 2; ++nf) {
                int r = wn * 32 + nf * 16 + li;
                int u = r * 64 + ((g ^ (r & 7)) * 8);
                bh[nf] = *(const f16x8*)&Bh[u];
            }
#pragma unroll
            for (int mf = 0; mf < 2; ++mf)
#pragma unroll
                for (int nf = 0; nf < 2; ++nf)
                    acc_h[mf][nf] = __builtin_amdgcn_mfma_f32_16x16x32_f16(
                        ah[mf], bh[nf], acc_h[mf][nf], 0, 0, 0);
        }
    }

    float bn[2];
    bn[0] = bias[n0 + wn * 32 + li];
    bn[1] = bias[n0 + wn * 32 + 16 + li];
#pragma unroll
    for (int mf = 0; mf < 2; ++mf) {
        int mb = m0 + wm * 32 + mf * 16 + lq * 4;
#pragma unroll
        for (int r = 0; r < 4; ++r) {
            size_t row = (size_t)(mb + r) * 256;
#pragma unroll
            for (int nf = 0; nf < 2; ++nf) {
                int n   = n0 + wn * 32 + nf * 16 + li;
                float v = acc_h[mf][nf][r] + bn[nf];
                v = fmaxf(v, 0.f) * 16.0f;        // x16 scale for prim A-side
                hh[row + n] = (f16)v;
            }
        }
    }
}

// ------------------------- prim conv: 256x256 block, BK=64, dbuf ------------
// GEMM: C[M=chunk*36, 256] += im2col(h16)[M,Kz] * W128[Kz,256], z=7 tap
// groups. acc = (16A)(128W) = 2048*C; epilogue /2048.
// LDS per buffer (32768 f16 = 64 KiB): A = 8 wave-chunks of 32 rows x 64 k,
// B same at +16384. Chunk layout [r][8 slots of 8 f16]; slot (r,e) holds
// logical k-col e^(r&7). dma16 #i lane l -> (r = i*8 + l>>3, e = l&7), so
// global source col = (l&7)^(l>>3) (same 128-B line, permuted). Frag read:
// sc = (ksub*2+half)^(r&7) -> 8-lane phase groups span all 32 banks.
// Pipeline: {stage(next); compute(cur); __syncthreads} (measured best).
__global__ void __launch_bounds__(512, 1) prim_mfma256(
    const f16* __restrict__ hh,
    const f16* __restrict__ whT,
    const float* __restrict__ bias, float* __restrict__ p, int b_base)
{
    __shared__ __align__(16) f16 lds[65536];      // 128 KiB, 2 buffers a 32768
    const int t  = threadIdx.x;
    const int m0 = blockIdx.x * 256;
    const int zi = blockIdx.y;                    // 0..6
    const int s_begin = (zi < 4) ? zi * 12 : 48 + (zi - 4) * 11;
    const int s_cnt   = (zi < 4) ? 12 : 11;
    const int nsteps  = s_cnt * 4;                // K-steps of 64 channels

    const int l  = t & 63, w = t >> 6;            // wave 0..7
    const int wm = w >> 2, wn = w & 3;            // 2 x 4 wave grid
    const int r  = l & 31, half = l >> 5;

    // ---- staging lane constants ----
    const int g  = l >> 3, e = l & 7;             // sub-row, stored slot
    const int cl = e ^ g;                         // logical k-col (x8 f16)
    int aoff[4], boff[4];
#pragma unroll
    for (int i = 0; i < 4; ++i) {
        int rc = i * 8 + g;                       // row within wave chunk
        int m  = m0 + 32 * w + rc;
        int bb = m / 36, pix = m - bb * 36;
        int py = pix / 6, px = pix - py * 6;
        aoff[i] = (bb * 400 + py * 40 + px * 2) * 256 + cl * 8;
        boff[i] = (32 * w + rc) * 20736 + cl * 8;
    }

    f32x16 acc[4][2];
#pragma unroll
    for (int i = 0; i < 4; ++i)
#pragma unroll
        for (int j = 0; j < 2; ++j)
#pragma unroll
            for (int ee = 0; ee < 16; ++ee) acc[i][j][ee] = 0.f;

    auto stage = [&](int buf, int step) {
        int s  = s_begin + (step >> 2);
        int kq = step & 3;
        int ky = s / 9, kx = s - ky * 9;
        int aAdd = (ky * 20 + kx) * 256 + kq * 64;
        int bAdd = s * 256 + kq * 64;
        f16* LA = &lds[buf * 32768 + w * 2048];
        f16* LB = &lds[buf * 32768 + 16384 + w * 2048];
#pragma unroll
        for (int i = 0; i < 4; ++i) {
            dma16(hh  + aoff[i] + aAdd, LA + i * 512);
            dma16(whT + boff[i] + bAdd, LB + i * 512);
        }
    };

    stage(0, 0);
    __syncthreads();                              // buf0 visible to all waves

    for (int ts = 0; ts < nsteps; ++ts) {
        const int buf = ts & 1;
        if (ts + 1 < nsteps) stage(buf ^ 1, ts + 1);   // prefetch next step
        __builtin_amdgcn_sched_barrier(0);             // keep DMA issue early
        const f16* LAc = &lds[buf * 32768 + wm * 8192];         // 4 chunks
        const f16* LBc = &lds[buf * 32768 + 16384 + wn * 4096]; // 2 chunks
        __builtin_amdgcn_s_setprio(1);
#pragma unroll
        for (int ksub = 0; ksub < 4; ++ksub) {
            const int sc = (ksub * 2 + half) ^ (r & 7);
            const int o  = r * 64 + sc * 8;
            f16x8 ah[4], bh[2];
#pragma unroll
            for (int mf = 0; mf < 4; ++mf)
                ah[mf] = *(const f16x8*)&LAc[mf * 2048 + o];
#pragma unroll
            for (int nf = 0; nf < 2; ++nf)
                bh[nf] = *(const f16x8*)&LBc[nf * 2048 + o];
#pragma unroll
            for (int mf = 0; mf < 4; ++mf)
#pragma unroll
                for (int nf = 0; nf < 2; ++nf)
                    acc[mf][nf] = __builtin_amdgcn_mfma_f32_32x32x16_f16(
                        ah[mf], bh[nf], acc[mf][nf], 0, 0, 0);
        }
        __builtin_amdgcn_s_setprio(0);
        __syncthreads();                               // drains DMA + reads done
    }

    // epilogue: C/D 32x32 layout: col = lane&31, row = (reg&3)+8*(reg>>2)+4*half
    float bn[2];
#pragma unroll
    for (int nf = 0; nf < 2; ++nf) {
        int n = wn * 64 + nf * 32 + r;
        bn[nf] = (zi == 0) ? bias[n] : 0.f;
    }
#pragma unroll
    for (int mf = 0; mf < 4; ++mf) {
#pragma unroll
        for (int reg = 0; reg < 16; ++reg) {
            int row = (reg & 3) + 8 * (reg >> 2) + 4 * half;
            int mm  = m0 + wm * 128 + mf * 32 + row;
            int b2  = mm / 36, pix2 = mm - b2 * 36;
            size_t rowp = (size_t)(b_base + b2) * 9216 + pix2 * 8;
#pragma unroll
            for (int nf = 0; nf < 2; ++nf) {
                int n   = wn * 64 + nf * 32 + r;
                int cap = n >> 3, vec = n & 7;
                float v = acc[mf][nf][reg] * (1.0f / 2048.0f) + bn[nf];
                atomicAdd(&p[rowp + cap * 288 + vec], v);
            }
        }
    }
}

// ------------------------- dynamic routing (register-priors) ----------------
// rwT layout: [c][i][r][v] -> q-load lane-coalesced (64-B chunks per thread,
// consecutive threads adjacent).
__global__ void __launch_bounds__(384) routing2(
    const float* __restrict__ p, const float* __restrict__ rwT,
    float* __restrict__ caps)
{
    const int b = blockIdx.x;
    const int c = blockIdx.y;
    const int t = threadIdx.x;
    const int lane = t & 63, wid = t >> 6;
    __shared__ float redbuf[6];
    __shared__ float tred[6][16];
    __shared__ float outv[16];

    const float* pb  = p   + (size_t)b * 9216;
    const float* rwc = rwT + (size_t)c * 8 * 1152 * 16;

    float q[3][16];
    float l[3] = {0.f, 0.f, 0.f};

#pragma unroll
    for (int j = 0; j < 3; ++j) {
        int r = t + 384 * j;
        float4 p0 = *(const float4*)&pb[r * 8];
        float4 p1 = *(const float4*)&pb[r * 8 + 4];
        float pr[8] = {p0.x, p0.y, p0.z, p0.w, p1.x, p1.y, p1.z, p1.w};
#pragma unroll
        for (int v = 0; v < 16; ++v) q[j][v] = 0.f;
#pragma unroll
        for (int i = 0; i < 8; ++i) {
            const float* wrow = rwc + ((size_t)(i * 1152 + r)) * 16;
#pragma unroll
            for (int v4 = 0; v4 < 4; ++v4) {
                float4 w4 = *(const float4*)&wrow[v4 * 4];
                q[j][v4 * 4 + 0] = fmaf(pr[i], w4.x, q[j][v4 * 4 + 0]);
                q[j][v4 * 4 + 1] = fmaf(pr[i], w4.y, q[j][v4 * 4 + 1]);
                q[j][v4 * 4 + 2] = fmaf(pr[i], w4.z, q[j][v4 * 4 + 2]);
                q[j][v4 * 4 + 3] = fmaf(pr[i], w4.w, q[j][v4 * 4 + 3]);
            }
        }
    }

    for (int it = 0; it < 3; ++it) {
        float lm = fmaxf(fmaxf(l[0], l[1]), l[2]);
#pragma unroll
        for (int off = 32; off; off >>= 1) lm = fmaxf(lm, __shfl_down(lm, off, 64));
        __syncthreads();
        if (lane == 0) redbuf[wid] = lm;
        __syncthreads();
        lm = fmaxf(fmaxf(fmaxf(redbuf[0], redbuf[1]), fmaxf(redbuf[2], redbuf[3])),
                   fmaxf(redbuf[4], redbuf[5]));

        float e[3];
        float ls = 0.f;
#pragma unroll
        for (int j = 0; j < 3; ++j) { e[j] = __expf(l[j] - lm); ls += e[j]; }
#pragma unroll
        for (int off = 32; off; off >>= 1) ls += __shfl_down(ls, off, 64);
        __syncthreads();
        if (lane == 0) redbuf[wid] = ls;
        __syncthreads();
        ls = redbuf[0] + redbuf[1] + redbuf[2] + redbuf[3] + redbuf[4] + redbuf[5];
        const float inv = 1.f / ls;

        float tv[16];
#pragma unroll
        for (int v = 0; v < 16; ++v)
            tv[v] = fmaf(e[0], q[0][v], fmaf(e[1], q[1][v], e[2] * q[2][v]));
#pragma unroll
        for (int v = 0; v < 16; ++v) {
            float xv = tv[v];
#pragma unroll
            for (int off = 32; off; off >>= 1) xv += __shfl_down(xv, off, 64);
            tv[v] = xv;
        }
        __syncthreads();
        if (lane == 0) {
#pragma unroll
            for (int v = 0; v < 16; ++v) tred[wid][v] = tv[v];
        }
        __syncthreads();
        if (t < 16)
            outv[t] = (tred[0][t] + tred[1][t] + tred[2][t]
                     + tred[3][t] + tred[4][t] + tred[5][t]) * inv;
        __syncthreads();

        float s2 = 0.f;
#pragma unroll
        for (int v = 0; v < 16; ++v) s2 += outv[v] * outv[v];
        const float scale = s2 / ((1.f + s2) * sqrtf(s2));

        if (it == 2) {
            if (t < 16) caps[((size_t)b * 2 + c) * 16 + t] = scale * outv[t];
        } else {
            float ov[16];
#pragma unroll
            for (int v = 0; v < 16; ++v) ov[v] = scale * outv[v];
#pragma unroll
            for (int j = 0; j < 3; ++j) {
                float d = 0.f;
#pragma unroll
                for (int v = 0; v < 16; ++v) d = fmaf(q[j][v], ov[v], d);
                l[j] += d;
            }
        }
    }
}

// ------------------------- class softmax + argmax mask ----------------------
__global__ void __launch_bounds__(256) mask_kernel(
    const float* __restrict__ caps, float* __restrict__ cls_out,
    float* __restrict__ masked)
{
    int b = blockIdx.x * 256 + threadIdx.x;
    if (b < 1024) {
        const float* cb = caps + (size_t)b * 32;
        float n0 = 0.f, n1 = 0.f;
#pragma unroll
        for (int v = 0; v < 16; ++v) {
            n0 = fmaf(cb[v], cb[v], n0);
            n1 = fmaf(cb[16 + v], cb[16 + v], n1);
        }
        n0 = sqrtf(n0); n1 = sqrtf(n1);
        float mx = fmaxf(n0, n1);
        float e0 = expf(n0 - mx), e1 = expf(n1 - mx);
        float inv = 1.f / (e0 + e1);
        cls_out[b * 2 + 0] = e0 * inv;
        cls_out[b * 2 + 1] = e1 * inv;
        int cs = (n1 > n0) ? 1 : 0;
#pragma unroll
        for (int v = 0; v < 16; ++v) {
            masked[(size_t)b * 32 + v]      = (cs == 0) ? cb[v] : 0.f;
            masked[(size_t)b * 32 + 16 + v] = (cs == 1) ? cb[16 + v] : 0.f;
        }
    }
}

// ------------------------- decoder GEMM -------------------------------------
template<int ACT>
__global__ void __launch_bounds__(256) dense_gemm(
    const float* __restrict__ A, const float* __restrict__ Bw,
    const float* __restrict__ bias, float* __restrict__ out,
    int M, int N, int K)
{
    __shared__ __align__(16) float As[16][128];
    __shared__ __align__(16) float Bs[16][64];
    const int t  = threadIdx.x;
    const int m0 = blockIdx.x * 128, n0 = blockIdx.y * 64;
    const int tx = t & 15, ty = t >> 4;
    const int am = t >> 1;
    const int ak = (t & 1) * 8;
    const int nb = (t & 15) * 4, kb = t >> 4;

    float acc[8][4];
#pragma unroll
    for (int i = 0; i < 8; ++i)
#pragma unroll
        for (int j = 0; j < 4; ++j) acc[i][j] = 0.f;

    for (int k0i = 0; k0i < K; k0i += 16) {
        {
            const float* ap = A + (size_t)(m0 + am) * K + k0i + ak;
            float4 v0 = *(const float4*)ap;
            float4 v1 = *(const float4*)(ap + 4);
            As[ak + 0][am] = v0.x; As[ak + 1][am] = v0.y;
            As[ak + 2][am] = v0.z; As[ak + 3][am] = v0.w;
            As[ak + 4][am] = v1.x; As[ak + 5][am] = v1.y;
            As[ak + 6][am] = v1.z; As[ak + 7][am] = v1.w;
        }
        {
            int k = k0i + kb;
            int n = n0 + nb;
            float4 v4 = make_float4(0.f, 0.f, 0.f, 0.f);
            if (n + 3 < N) {
                v4 = *(const float4*)&Bw[(size_t)k * N + n];
            } else {
                float tmp[4] = {0.f, 0.f, 0.f, 0.f};
#pragma unroll
                for (int e = 0; e < 4; ++e)
                    if (n + e < N) tmp[e] = Bw[(size_t)k * N + n + e];
                v4 = make_float4(tmp[0], tmp[1], tmp[2], tmp[3]);
            }
            *(float4*)&Bs[kb][nb] = v4;
        }
        __syncthreads();
#pragma unroll
        for (int kk = 0; kk < 16; ++kk) {
            float4 a0 = *(const float4*)&As[kk][ty * 8];
            float4 a1 = *(const float4*)&As[kk][ty * 8 + 4];
            float4 b0 = *(const float4*)&Bs[kk][tx * 4];
            float av[8] = {a0.x, a0.y, a0.z, a0.w, a1.x, a1.y, a1.z, a1.w};
            float bv[4] = {b0.x, b0.y, b0.z, b0.w};
#pragma unroll
            for (int i = 0; i < 8; ++i)
#pragma unroll
                for (int j = 0; j < 4; ++j)
                    acc[i][j] = fmaf(av[i], bv[j], acc[i][j]);
        }
        __syncthreads();
    }
#pragma unroll
    for (int i = 0; i < 8; ++i) {
        int mm = m0 + ty * 8 + i;
#pragma unroll
        for (int j = 0; j < 4; ++j) {
            int n = n0 + tx * 4 + j;
            if (n < N) {
                float v = acc[i][j] + bias[n];
                v = (ACT == 0) ? fmaxf(v, 0.f) : 1.f / (1.f + expf(-v));
                out[(size_t)mm * N + n] = v;
            }
        }
    }
}

// ------------------------- host launcher ------------------------------------
extern "C" void kernel_launch(void* const* d_in, const int* in_sizes, int n_in,
                              void* d_out, int out_size, void* d_ws, size_t ws_size,
                              hipStream_t stream)
{
    const float* x       = (const float*)d_in[0];
    const float* conv1_w = (const float*)d_in[1];
    const float* conv1_b = (const float*)d_in[2];
    const float* prim_w  = (const float*)d_in[3];
    const float* prim_b  = (const float*)d_in[4];
    const float* route_w = (const float*)d_in[5];
    const float* dec_w1  = (const float*)d_in[6];
    const float* dec_b1  = (const float*)d_in[7];
    const float* dec_w2  = (const float*)d_in[8];
    const float* dec_b2  = (const float*)d_in[9];
    const float* dec_w3  = (const float*)d_in[10];
    const float* dec_b3  = (const float*)d_in[11];

    f16*   whT1 = (f16*)d_ws;                       //   65536 halves
    f16*   whT  = whT1 + 65536;                     // 5308416 halves
    float* rwT    = (float*)(whT + 5308416);        //  294912 f32
    float* pbuf   = rwT + 294912;                   // 9437184 f32
    float* caps   = pbuf + 9437184;
    float* masked = caps + 32768;
    float* d1     = masked + 32768;
    float* d2     = d1 + 524288;
    f16*   hbase  = (f16*)(d2 + 1048576);
    float* outF   = (float*)d_out;

    const size_t fixed_bytes = 56229888ull;
    int chunk = 64;
    const int cand[4] = {512, 256, 128, 64};
    for (int i = 0; i < 4; ++i) {
        if (fixed_bytes + (size_t)cand[i] * 204800ull <= ws_size) {
            chunk = cand[i];
            break;
        }
    }
    if (chunk > 256) chunk = 256;                   // hh sized per chunk
    f16* hh = hbase;

    // p accumulated via atomics (split-K) -> zero it
    hipMemsetAsync(pbuf, 0, 9437184ull * sizeof(float), stream);

    w1prep<<<256, 256, 0, stream>>>(conv1_w, whT1);
    transpose_w<<<dim3(256, 4), 256, 0, stream>>>(prim_w, whT);
    transpose_rw<<<dim3(1152, 2), 128, 0, stream>>>(route_w, rwT);

    const int nchunks = 1024 / chunk;
    for (int ci = 0; ci < nchunks; ++ci) {
        const float* xin = x + (size_t)ci * chunk * 2352;
        conv1_mfma<<<dim3(chunk * 400 / 64, 4), 256, 0, stream>>>(
            xin, whT1, conv1_b, hh);
        prim_mfma256<<<dim3(chunk * 36 / 256, 7), 512, 0, stream>>>(
            hh, whT, prim_b, pbuf, ci * chunk);
    }

    routing2<<<dim3(1024, 2), 384, 0, stream>>>(pbuf, rwT, caps);
    mask_kernel<<<4, 256, 0, stream>>>(caps, outF, masked);

    dense_gemm<0><<<dim3(8, 8),  256, 0, stream>>>(masked, dec_w1, dec_b1, d1, 1024, 512, 32);
    dense_gemm<0><<<dim3(8, 16), 256, 0, stream>>>(d1, dec_w2, dec_b2, d2, 1024, 1024, 512);
    dense_gemm<1><<<dim3(8, 13), 256, 0, stream>>>(d2, dec_w3, dec_b3, outF + 2048, 1024, 784, 1024);
}